// Round 1
// baseline (1233.288 us; speedup 1.0000x reference)
//
#include <hip/hip_runtime.h>

// ---------------- CSR build ----------------
__global__ __launch_bounds__(256) void count_k(const int* __restrict__ src,
    const int* __restrict__ dst, int* __restrict__ deg, int* __restrict__ cnt, int E) {
  int e = blockIdx.x * 256 + threadIdx.x;
  if (e < E) {
    atomicAdd(&deg[src[e]], 1);
    atomicAdd(&cnt[dst[e]], 1);
  }
}

__global__ __launch_bounds__(256) void scan1_k(const int* __restrict__ cnt,
    int* __restrict__ off, int* __restrict__ bsum, int N) {
  __shared__ int s[256];
  int t = threadIdx.x;
  int i = blockIdx.x * 256 + t;
  int c = (i < N) ? cnt[i] : 0;
  s[t] = c;
  __syncthreads();
  for (int d = 1; d < 256; d <<= 1) {
    int v = (t >= d) ? s[t - d] : 0;
    __syncthreads();
    s[t] += v;
    __syncthreads();
  }
  if (i < N) off[i + 1] = s[t];
  if (t == 255) bsum[blockIdx.x] = s[255];
}

__global__ __launch_bounds__(256) void scan2_k(int* __restrict__ bsum, int NB) {
  __shared__ int s[256];
  int t = threadIdx.x;
  int c = (t < NB) ? bsum[t] : 0;
  s[t] = c;
  __syncthreads();
  for (int d = 1; d < 256; d <<= 1) {
    int v = (t >= d) ? s[t - d] : 0;
    __syncthreads();
    s[t] += v;
    __syncthreads();
  }
  if (t < NB) bsum[t] = s[t] - c;  // exclusive
}

__global__ __launch_bounds__(256) void scan3_k(int* __restrict__ off,
    const int* __restrict__ bsum, int N) {
  int i = blockIdx.x * 256 + threadIdx.x;
  if (i < N) off[i + 1] += bsum[blockIdx.x];
  if (i == 0) off[0] = 0;
}

__global__ __launch_bounds__(256) void fill_k(const int* __restrict__ src,
    const int* __restrict__ dst, const int* __restrict__ off,
    int* __restrict__ cur, int* __restrict__ csr, int E) {
  int e = blockIdx.x * 256 + threadIdx.x;
  if (e < E) {
    int d = dst[e];
    int p = off[d] + atomicAdd(&cur[d], 1);
    csr[p] = src[e];
  }
}

// ---------------- input features ----------------
__global__ void root_k(const int* __restrict__ root, int* __restrict__ egof, int G) {
  int g = threadIdx.x;
  if (g < G) egof[root[g]] = 1;
}

// h0 = [x | deg_table[min(deg,128)] | ego], row stride 72 (16B-aligned rows).
// Fused global_add_pool of h0 into pool0 (stride 72).
__global__ __launch_bounds__(256) void h0_k(const float* __restrict__ x,
    const float* __restrict__ deg_table, const int* __restrict__ deg,
    const int* __restrict__ egof, const int* __restrict__ batch,
    float* __restrict__ h0, float* __restrict__ pool0, int N) {
  int idx = blockIdx.x * 256 + threadIdx.x;
  int n = idx >> 6, f = idx & 63;
  if (n >= N) return;
  n = __builtin_amdgcn_readfirstlane(n);
  float v;
  if (f < 32) {
    v = x[n * 32 + f];
  } else {
    int d = deg[n];
    if (d > 128) d = 128;
    v = deg_table[d * 32 + (f - 32)];
  }
  h0[(size_t)n * 72 + f] = v;
  int b = batch[n];
  atomicAdd(&pool0[b * 72 + f], v);
  if (f == 0) {
    float e = egof[n] ? 1.0f : 0.0f;
    h0[(size_t)n * 72 + 64] = e;
    if (e != 0.0f) atomicAdd(&pool0[b * 72 + 64], 1.0f);
  }
}

// ---------------- aggregation: z[n] = h[n] + sum_{src in CSR(n)} h[src] ----------------
template <int FEATS, int STRIDE>
__global__ __launch_bounds__(256) void aggregate_k(const float* __restrict__ h,
    const int* __restrict__ off, const int* __restrict__ csr,
    float* __restrict__ z, int N) {
  int wid = (blockIdx.x * 256 + threadIdx.x) >> 6;
  int lane = threadIdx.x & 63;
  if (wid >= N) return;
  wid = __builtin_amdgcn_readfirstlane(wid);
  int k0 = off[wid], k1 = off[wid + 1];
  float acc = h[(size_t)wid * STRIDE + lane];
  float accB = 0.0f;
  if (FEATS == 65 && lane == 0) accB = h[(size_t)wid * STRIDE + 64];
  int k = k0;
  for (; k + 2 <= k1; k += 2) {
    int s0 = csr[k], s1 = csr[k + 1];
    acc += h[(size_t)s0 * STRIDE + lane];
    acc += h[(size_t)s1 * STRIDE + lane];
    if (FEATS == 65 && lane == 0)
      accB += h[(size_t)s0 * STRIDE + 64] + h[(size_t)s1 * STRIDE + 64];
  }
  if (k < k1) {
    int s0 = csr[k];
    acc += h[(size_t)s0 * STRIDE + lane];
    if (FEATS == 65 && lane == 0) accB += h[(size_t)s0 * STRIDE + 64];
  }
  z[(size_t)wid * STRIDE + lane] = acc;
  if (FEATS == 65 && lane == 0) z[(size_t)wid * STRIDE + 64] = accB;
}

// ---------------- node-wise GEMM: out[i,:] = f(in[i,:]) @ W + B ----------------
// PRE_BN applies relu(v*bnp[k]+bnp[64+k]) to inputs (fused BN0+ReLU before MLP linear 2).
template <int DIN, bool PRE_BN>
__global__ __launch_bounds__(256) void gemm_k(const float* __restrict__ in, int istride,
    const float* __restrict__ W, const float* __restrict__ B,
    const float* __restrict__ bnp, float* __restrict__ out, int N) {
  int i = blockIdx.x * 256 + threadIdx.x;
  if (i >= N) return;
  float acc[64];
#pragma unroll
  for (int j = 0; j < 64; j++) acc[j] = B[j];
  const float* row = in + (size_t)i * istride;
#pragma unroll 1
  for (int k4 = 0; k4 < DIN / 4; k4++) {
    float4 c4 = *(const float4*)(row + k4 * 4);
    float cv[4] = {c4.x, c4.y, c4.z, c4.w};
#pragma unroll
    for (int kk = 0; kk < 4; kk++) {
      int k = k4 * 4 + kk;
      float v = cv[kk];
      if (PRE_BN) v = fmaxf(v * bnp[k] + bnp[64 + k], 0.0f);
#pragma unroll
      for (int j = 0; j < 64; j++) acc[j] += v * W[k * 64 + j];
    }
  }
  if (DIN & 3) {
    for (int k = (DIN / 4) * 4; k < DIN; k++) {
      float v = row[k];
      if (PRE_BN) v = fmaxf(v * bnp[k] + bnp[64 + k], 0.0f);
#pragma unroll
      for (int j = 0; j < 64; j++) acc[j] += v * W[k * 64 + j];
    }
  }
  float* orow = out + (size_t)i * 64;
#pragma unroll
  for (int j = 0; j < 64; j += 4)
    *(float4*)(orow + j) = make_float4(acc[j], acc[j + 1], acc[j + 2], acc[j + 3]);
}

// ---------------- per-feature sum / sumsq (optionally of relu(bn(x))) ----------------
template <bool BNRELU>
__global__ __launch_bounds__(256) void stats_k(const float* __restrict__ in,
    const float* __restrict__ bnp, float* __restrict__ sums, int N) {
  int f = threadIdx.x & 63;
  int r = threadIdx.x >> 6;
  float sc = 0.0f, sh = 0.0f;
  if (BNRELU) { sc = bnp[f]; sh = bnp[64 + f]; }
  float s = 0.0f, q = 0.0f;
  for (int n = blockIdx.x * 4 + r; n < N; n += gridDim.x * 4) {
    float v = in[(size_t)n * 64 + f];
    if (BNRELU) v = fmaxf(v * sc + sh, 0.0f);
    s += v;
    q += v * v;
  }
  __shared__ float ss[256], sq[256];
  ss[threadIdx.x] = s;
  sq[threadIdx.x] = q;
  __syncthreads();
  if (threadIdx.x < 64) {
    s = ss[f] + ss[64 + f] + ss[128 + f] + ss[192 + f];
    q = sq[f] + sq[64 + f] + sq[128 + f] + sq[192 + f];
    atomicAdd(&sums[f], s);
    atomicAdd(&sums[64 + f], q);
  }
}

__global__ void bn_fin_k(const float* __restrict__ sums, const float* __restrict__ gamma,
    const float* __restrict__ beta, float* __restrict__ bnp, float invN) {
  int f = threadIdx.x;
  float m = sums[f] * invN;
  float var = sums[64 + f] * invN - m * m;
  float sc = gamma[f] * rsqrtf(var + 1e-5f);
  bnp[f] = sc;
  bnp[64 + f] = beta[f] - m * sc;
}

// h_out = relu(bn2(relu(bn1(z2)))), fused global_add_pool into pool (stride 64)
__global__ __launch_bounds__(256) void apply_k(const float* __restrict__ z2,
    const float* __restrict__ bnp1, const float* __restrict__ bnp2,
    const int* __restrict__ batch, float* __restrict__ hout,
    float* __restrict__ pool, int N) {
  int idx = blockIdx.x * 256 + threadIdx.x;
  int n = idx >> 6, f = idx & 63;
  if (n >= N) return;
  n = __builtin_amdgcn_readfirstlane(n);
  float v = z2[(size_t)n * 64 + f];
  v = fmaxf(v * bnp1[f] + bnp1[64 + f], 0.0f);
  v = fmaxf(v * bnp2[f] + bnp2[64 + f], 0.0f);
  hout[(size_t)n * 64 + f] = v;
  atomicAdd(&pool[batch[n] * 64 + f], v);
}

// score[g,j] += pool[g,:] @ W[:,j] + B[j]
__global__ __launch_bounds__(256) void pred_k(const float* __restrict__ pool, int pstride,
    int din, const float* __restrict__ W, const float* __restrict__ B,
    float* __restrict__ score, int G) {
  int idx = blockIdx.x * 256 + threadIdx.x;
  if (idx >= G * 32) return;
  int g = idx >> 5, j = idx & 31;
  float acc = B[j];
  for (int k = 0; k < din; k++) acc += pool[g * pstride + k] * W[k * 32 + j];
  score[idx] += acc;
}

__global__ void norm_k(const float* __restrict__ score, float* __restrict__ out, int G) {
  int g = blockIdx.x * blockDim.x + threadIdx.x;
  if (g >= G) return;
  float s = 0.0f;
  float v[32];
#pragma unroll
  for (int j = 0; j < 32; j++) {
    v[j] = score[g * 32 + j];
    s += v[j] * v[j];
  }
  float nrm = fmaxf(sqrtf(s), 1e-5f);
#pragma unroll
  for (int j = 0; j < 32; j++) out[g * 32 + j] = v[j] / nrm;
}

extern "C" void kernel_launch(void* const* d_in, const int* in_sizes, int n_in,
                              void* d_out, int out_size, void* d_ws, size_t ws_size,
                              hipStream_t stream) {
  (void)n_in; (void)out_size; (void)ws_size;
  const float* x          = (const float*)d_in[0];
  const int*   edge_index = (const int*)d_in[1];
  const int*   batch      = (const int*)d_in[2];
  const int*   root       = (const int*)d_in[3];
  const float* deg_table  = (const float*)d_in[4];
  const float* w1_0       = (const float*)d_in[5];
  const float* b1_0       = (const float*)d_in[6];
  const float* w2_0       = (const float*)d_in[7];
  const float* b2_0       = (const float*)d_in[8];
  const float* w1_rest    = (const float*)d_in[9];
  const float* b1_rest    = (const float*)d_in[10];
  const float* w2_rest    = (const float*)d_in[11];
  const float* b2_rest    = (const float*)d_in[12];
  const float* bn_gamma   = (const float*)d_in[13];
  const float* bn_beta    = (const float*)d_in[14];
  const float* pred_w0    = (const float*)d_in[15];
  const float* pred_b0    = (const float*)d_in[16];
  const float* pred_w_rest = (const float*)d_in[17];
  const float* pred_b_rest = (const float*)d_in[18];

  const int N = in_sizes[0] / 32;
  const int E = in_sizes[1] / 2;
  const int G = in_sizes[3];
  const int* src = edge_index;
  const int* dst = edge_index + E;

  // ---- workspace carve-up (256B aligned) ----
  char* w = (char*)d_ws;
  auto alloc = [&](size_t bytes) {
    char* p = w;
    w += (bytes + 255) & ~(size_t)255;
    return p;
  };
  int* d_deg  = (int*)alloc((size_t)N * 4);
  int* d_egof = (int*)alloc((size_t)N * 4);
  int* d_cnt  = (int*)alloc((size_t)N * 4);
  int* d_cur  = (int*)alloc((size_t)N * 4);
  char* zero_int_end = w;
  int* d_off  = (int*)alloc((size_t)(N + 1) * 4);
  int* d_bsum = (int*)alloc(256 * 4);
  int* d_csr  = (int*)alloc((size_t)E * 4);
  float* fsums  = (float*)alloc(15 * 128 * 4);
  float* fpool  = (float*)alloc((size_t)(G * 72 + 5 * G * 64) * 4);
  float* fscore = (float*)alloc((size_t)G * 32 * 4);
  char* zero_f_end = w;
  float* fbnp = (float*)alloc(15 * 128 * 4);
  float* fh0  = (float*)alloc((size_t)N * 72 * 4);
  float* fB1  = (float*)alloc((size_t)N * 72 * 4);
  float* fB2  = (float*)alloc((size_t)N * 64 * 4);
  float* fB3  = (float*)alloc((size_t)N * 64 * 4);

  hipMemsetAsync(d_deg, 0, (size_t)(zero_int_end - (char*)d_deg), stream);
  hipMemsetAsync(fsums, 0, (size_t)(zero_f_end - (char*)fsums), stream);

  const int ebl = (E + 255) / 256;
  const int nb  = (N + 255) / 256;       // <=256 tiles assumed (N<=65536)
  const int nwb = (N * 64 + 255) / 256;  // thread per (node,feature)

  count_k<<<ebl, 256, 0, stream>>>(src, dst, d_deg, d_cnt, E);
  scan1_k<<<nb, 256, 0, stream>>>(d_cnt, d_off, d_bsum, N);
  scan2_k<<<1, 256, 0, stream>>>(d_bsum, nb);
  scan3_k<<<nb, 256, 0, stream>>>(d_off, d_bsum, N);
  fill_k<<<ebl, 256, 0, stream>>>(src, dst, d_off, d_cur, d_csr, E);
  root_k<<<1, 256, 0, stream>>>(root, d_egof, G);
  h0_k<<<nwb, 256, 0, stream>>>(x, deg_table, d_deg, d_egof, batch, fh0, fpool, N);
  pred_k<<<(G * 32 + 255) / 256, 256, 0, stream>>>(fpool, 72, 65, pred_w0, pred_b0, fscore, G);

  const float* hcur = fh0;
  for (int l = 0; l < 5; l++) {
    float* zb  = fB1;                          // z = h+agg, then reused as z2
    float* z1b = (l % 2 == 0) ? fB2 : fB3;     // z1, then reused as h_out
    if (l == 0) aggregate_k<65, 72><<<nwb, 256, 0, stream>>>(hcur, d_off, d_csr, zb, N);
    else        aggregate_k<64, 64><<<nwb, 256, 0, stream>>>(hcur, d_off, d_csr, zb, N);

    const float* w1 = (l == 0) ? w1_0 : w1_rest + (size_t)(l - 1) * 64 * 64;
    const float* b1 = (l == 0) ? b1_0 : b1_rest + (size_t)(l - 1) * 64;
    const float* w2 = (l == 0) ? w2_0 : w2_rest + (size_t)(l - 1) * 64 * 64;
    const float* b2 = (l == 0) ? b2_0 : b2_rest + (size_t)(l - 1) * 64;
    float* sums0 = fsums + (l * 3 + 0) * 128;
    float* sums1 = fsums + (l * 3 + 1) * 128;
    float* sums2 = fsums + (l * 3 + 2) * 128;
    float* bnp0 = fbnp + (l * 3 + 0) * 128;
    float* bnp1 = fbnp + (l * 3 + 1) * 128;
    float* bnp2 = fbnp + (l * 3 + 2) * 128;

    if (l == 0) gemm_k<65, false><<<nb, 256, 0, stream>>>(zb, 72, w1, b1, nullptr, z1b, N);
    else        gemm_k<64, false><<<nb, 256, 0, stream>>>(zb, 64, w1, b1, nullptr, z1b, N);
    stats_k<false><<<256, 256, 0, stream>>>(z1b, nullptr, sums0, N);
    bn_fin_k<<<1, 64, 0, stream>>>(sums0, bn_gamma + (l * 3 + 0) * 64,
                                   bn_beta + (l * 3 + 0) * 64, bnp0, 1.0f / N);
    gemm_k<64, true><<<nb, 256, 0, stream>>>(z1b, 64, w2, b2, bnp0, zb, N);
    stats_k<false><<<256, 256, 0, stream>>>(zb, nullptr, sums1, N);
    bn_fin_k<<<1, 64, 0, stream>>>(sums1, bn_gamma + (l * 3 + 1) * 64,
                                   bn_beta + (l * 3 + 1) * 64, bnp1, 1.0f / N);
    stats_k<true><<<256, 256, 0, stream>>>(zb, bnp1, sums2, N);
    bn_fin_k<<<1, 64, 0, stream>>>(sums2, bn_gamma + (l * 3 + 2) * 64,
                                   bn_beta + (l * 3 + 2) * 64, bnp2, 1.0f / N);

    float* pool_l = fpool + G * 72 + (size_t)l * G * 64;
    apply_k<<<nwb, 256, 0, stream>>>(zb, bnp1, bnp2, batch, z1b, pool_l, N);
    pred_k<<<(G * 32 + 255) / 256, 256, 0, stream>>>(pool_l, 64, 64,
        pred_w_rest + (size_t)l * 64 * 32, pred_b_rest + (size_t)l * 32, fscore, G);
    hcur = z1b;
  }
  norm_k<<<1, 256, 0, stream>>>(fscore, (float*)d_out, G);
}

// Round 2
// 1072.932 us; speedup vs baseline: 1.1495x; 1.1495x over previous
//
#include <hip/hip_runtime.h>

// ---------------- CSR build ----------------
__global__ __launch_bounds__(256) void count_k(const int* __restrict__ src,
    const int* __restrict__ dst, int* __restrict__ deg, int* __restrict__ cnt, int E) {
  int e = blockIdx.x * 256 + threadIdx.x;
  if (e < E) {
    atomicAdd(&deg[src[e]], 1);
    atomicAdd(&cnt[dst[e]], 1);
  }
}

__global__ __launch_bounds__(256) void scan1_k(const int* __restrict__ cnt,
    int* __restrict__ off, int* __restrict__ bsum, int N) {
  __shared__ int s[256];
  int t = threadIdx.x;
  int i = blockIdx.x * 256 + t;
  int c = (i < N) ? cnt[i] : 0;
  s[t] = c;
  __syncthreads();
  for (int d = 1; d < 256; d <<= 1) {
    int v = (t >= d) ? s[t - d] : 0;
    __syncthreads();
    s[t] += v;
    __syncthreads();
  }
  if (i < N) off[i + 1] = s[t];
  if (t == 255) bsum[blockIdx.x] = s[255];
}

__global__ __launch_bounds__(256) void scan2_k(int* __restrict__ bsum, int NB) {
  __shared__ int s[256];
  int t = threadIdx.x;
  int c = (t < NB) ? bsum[t] : 0;
  s[t] = c;
  __syncthreads();
  for (int d = 1; d < 256; d <<= 1) {
    int v = (t >= d) ? s[t - d] : 0;
    __syncthreads();
    s[t] += v;
    __syncthreads();
  }
  if (t < NB) bsum[t] = s[t] - c;  // exclusive
}

__global__ __launch_bounds__(256) void scan3_k(int* __restrict__ off,
    const int* __restrict__ bsum, int N) {
  int i = blockIdx.x * 256 + threadIdx.x;
  if (i < N) off[i + 1] += bsum[blockIdx.x];
  if (i == 0) off[0] = 0;
}

__global__ __launch_bounds__(256) void fill_k(const int* __restrict__ src,
    const int* __restrict__ dst, const int* __restrict__ off,
    int* __restrict__ cur, int* __restrict__ csr, int E) {
  int e = blockIdx.x * 256 + threadIdx.x;
  if (e < E) {
    int d = dst[e];
    int p = off[d] + atomicAdd(&cur[d], 1);
    csr[p] = src[e];
  }
}

__global__ void root_k(const int* __restrict__ root, int* __restrict__ egof, int G) {
  int g = threadIdx.x;
  if (g < G) egof[root[g]] = 1;
}

// h0 = [x | deg_table[min(deg,128)] | ego], row stride 72; segmented pool into pool0.
// batch is sorted -> per-wave running sum, flush one atomic per graph boundary.
__global__ __launch_bounds__(256) void h0_k(const float* __restrict__ x,
    const float* __restrict__ deg_table, const int* __restrict__ deg,
    const int* __restrict__ egof, const int* __restrict__ batch,
    float* __restrict__ h0, float* __restrict__ pool0, int N) {
  int w = threadIdx.x >> 6, f = threadIdx.x & 63;
  int base = blockIdx.x * 256;
  int end = min(base + 256, N);
  float accum = 0.0f, accum64 = 0.0f;
  int curg = -1;
  for (int n0 = base + w; n0 < end; n0 += 4) {
    int n = __builtin_amdgcn_readfirstlane(n0);
    float v;
    if (f < 32) {
      v = x[n * 32 + f];
    } else {
      int d = deg[n];
      if (d > 128) d = 128;
      v = deg_table[d * 32 + (f - 32)];
    }
    h0[(size_t)n * 72 + f] = v;
    float e = 0.0f;
    if (f == 0) {
      e = egof[n] ? 1.0f : 0.0f;
      h0[(size_t)n * 72 + 64] = e;
    }
    int g = batch[n];
    if (g != curg) {
      if (curg >= 0) {
        atomicAdd(&pool0[curg * 72 + f], accum);
        if (f == 0 && accum64 != 0.0f) atomicAdd(&pool0[curg * 72 + 64], accum64);
      }
      curg = g;
      accum = v;
      accum64 = e;
    } else {
      accum += v;
      accum64 += e;
    }
  }
  if (curg >= 0) {
    atomicAdd(&pool0[curg * 72 + f], accum);
    if (f == 0 && accum64 != 0.0f) atomicAdd(&pool0[curg * 72 + 64], accum64);
  }
}

// ---------------- aggregation: z[n] = h[n] + sum_{src in CSR(n)} h[src] ----------------
template <int FEATS, int STRIDE>
__global__ __launch_bounds__(256) void aggregate_k(const float* __restrict__ h,
    const int* __restrict__ off, const int* __restrict__ csr,
    float* __restrict__ z, int N) {
  int wid = (blockIdx.x * 256 + threadIdx.x) >> 6;
  int lane = threadIdx.x & 63;
  if (wid >= N) return;
  wid = __builtin_amdgcn_readfirstlane(wid);
  int k0 = off[wid], k1 = off[wid + 1];
  float acc = h[(size_t)wid * STRIDE + lane];
  float accB = 0.0f;
  if (FEATS == 65 && lane == 0) accB = h[(size_t)wid * STRIDE + 64];
  int k = k0;
  for (; k + 2 <= k1; k += 2) {
    int s0 = csr[k], s1 = csr[k + 1];
    acc += h[(size_t)s0 * STRIDE + lane];
    acc += h[(size_t)s1 * STRIDE + lane];
    if (FEATS == 65 && lane == 0)
      accB += h[(size_t)s0 * STRIDE + 64] + h[(size_t)s1 * STRIDE + 64];
  }
  if (k < k1) {
    int s0 = csr[k];
    acc += h[(size_t)s0 * STRIDE + lane];
    if (FEATS == 65 && lane == 0) accB += h[(size_t)s0 * STRIDE + 64];
  }
  z[(size_t)wid * STRIDE + lane] = acc;
  if (FEATS == 65 && lane == 0) z[(size_t)wid * STRIDE + 64] = accB;
}

// ---------------- node-wise GEMM: out[i,:] = f(in[i,:]) @ W + B ----------------
// PRE_BN computes bn scale/shift from (sums,gamma,beta) in-block, applies relu(bn(v)).
template <int DIN, bool PRE_BN>
__global__ __launch_bounds__(256) void gemm_k(const float* __restrict__ in, int istride,
    const float* __restrict__ W, const float* __restrict__ B,
    const float* __restrict__ sums, const float* __restrict__ gamma,
    const float* __restrict__ beta, float invN, float* __restrict__ out, int N) {
  __shared__ float psc[64], psh[64];
  if (PRE_BN) {
    int t = threadIdx.x;
    if (t < 64) {
      float m = sums[t] * invN;
      float var = sums[64 + t] * invN - m * m;
      float sc = gamma[t] * rsqrtf(var + 1e-5f);
      psc[t] = sc;
      psh[t] = beta[t] - m * sc;
    }
    __syncthreads();
  }
  int i = blockIdx.x * 256 + threadIdx.x;
  if (i >= N) return;
  float acc[64];
#pragma unroll
  for (int j = 0; j < 64; j++) acc[j] = B[j];
  const float* row = in + (size_t)i * istride;
#pragma unroll 1
  for (int k4 = 0; k4 < DIN / 4; k4++) {
    float4 c4 = *(const float4*)(row + k4 * 4);
    float cv[4] = {c4.x, c4.y, c4.z, c4.w};
#pragma unroll
    for (int kk = 0; kk < 4; kk++) {
      int k = k4 * 4 + kk;
      float v = cv[kk];
      if (PRE_BN) v = fmaxf(v * psc[k] + psh[k], 0.0f);
#pragma unroll
      for (int j = 0; j < 64; j++) acc[j] += v * W[k * 64 + j];
    }
  }
  if (DIN & 3) {
    for (int k = (DIN / 4) * 4; k < DIN; k++) {
      float v = row[k];
      if (PRE_BN) v = fmaxf(v * psc[k] + psh[k], 0.0f);
#pragma unroll
      for (int j = 0; j < 64; j++) acc[j] += v * W[k * 64 + j];
    }
  }
  float* orow = out + (size_t)i * 64;
#pragma unroll
  for (int j = 0; j < 64; j += 4)
    *(float4*)(orow + j) = make_float4(acc[j], acc[j + 1], acc[j + 2], acc[j + 3]);
}

// ---------------- per-feature sum / sumsq ----------------
__global__ __launch_bounds__(256) void stats_plain_k(const float* __restrict__ in,
    float* __restrict__ sums, int N) {
  int f = threadIdx.x & 63;
  int r = threadIdx.x >> 6;
  float s = 0.0f, q = 0.0f;
  for (int n = blockIdx.x * 4 + r; n < N; n += gridDim.x * 4) {
    float v = in[(size_t)n * 64 + f];
    s += v;
    q += v * v;
  }
  __shared__ float ss[256], sq[256];
  ss[threadIdx.x] = s;
  sq[threadIdx.x] = q;
  __syncthreads();
  if (threadIdx.x < 64) {
    s = ss[f] + ss[64 + f] + ss[128 + f] + ss[192 + f];
    q = sq[f] + sq[64 + f] + sq[128 + f] + sq[192 + f];
    atomicAdd(&sums[f], s);
    atomicAdd(&sums[64 + f], q);
  }
}

// stats of relu(bn1(in)); bn1 computed in-block from sums1
__global__ __launch_bounds__(256) void stats_bn_k(const float* __restrict__ in,
    const float* __restrict__ sums1, const float* __restrict__ gamma,
    const float* __restrict__ beta, float invN, float* __restrict__ sums, int N) {
  __shared__ float psc[64], psh[64];
  int t = threadIdx.x;
  if (t < 64) {
    float m = sums1[t] * invN;
    float var = sums1[64 + t] * invN - m * m;
    float sc = gamma[t] * rsqrtf(var + 1e-5f);
    psc[t] = sc;
    psh[t] = beta[t] - m * sc;
  }
  __syncthreads();
  int f = t & 63;
  int r = t >> 6;
  float sc = psc[f], sh = psh[f];
  float s = 0.0f, q = 0.0f;
  for (int n = blockIdx.x * 4 + r; n < N; n += gridDim.x * 4) {
    float v = in[(size_t)n * 64 + f];
    v = fmaxf(v * sc + sh, 0.0f);
    s += v;
    q += v * v;
  }
  __shared__ float ss[256], sq[256];
  ss[t] = s;
  sq[t] = q;
  __syncthreads();
  if (t < 64) {
    s = ss[f] + ss[64 + f] + ss[128 + f] + ss[192 + f];
    q = sq[f] + sq[64 + f] + sq[128 + f] + sq[192 + f];
    atomicAdd(&sums[f], s);
    atomicAdd(&sums[64 + f], q);
  }
}

// h_out = relu(bn2(relu(bn1(z2)))); bn params computed in-block; segmented pool.
__global__ __launch_bounds__(256) void apply_k(const float* __restrict__ z2,
    const float* __restrict__ sums1, const float* __restrict__ g1, const float* __restrict__ b1,
    const float* __restrict__ sums2, const float* __restrict__ g2, const float* __restrict__ b2,
    float invN, const int* __restrict__ batch, float* __restrict__ hout,
    float* __restrict__ pool, int N, int writeH) {
  __shared__ float sc1s[64], sh1s[64], sc2s[64], sh2s[64];
  int t = threadIdx.x;
  if (t < 64) {
    float m = sums1[t] * invN;
    float var = sums1[64 + t] * invN - m * m;
    float s = g1[t] * rsqrtf(var + 1e-5f);
    sc1s[t] = s;
    sh1s[t] = b1[t] - m * s;
    m = sums2[t] * invN;
    var = sums2[64 + t] * invN - m * m;
    s = g2[t] * rsqrtf(var + 1e-5f);
    sc2s[t] = s;
    sh2s[t] = b2[t] - m * s;
  }
  __syncthreads();
  int w = t >> 6, f = t & 63;
  float sc1 = sc1s[f], sh1 = sh1s[f], sc2 = sc2s[f], sh2 = sh2s[f];
  int base = blockIdx.x * 256;
  int end = min(base + 256, N);
  float accum = 0.0f;
  int curg = -1;
  for (int n0 = base + w; n0 < end; n0 += 4) {
    int n = __builtin_amdgcn_readfirstlane(n0);
    float v = z2[(size_t)n * 64 + f];
    v = fmaxf(v * sc1 + sh1, 0.0f);
    v = fmaxf(v * sc2 + sh2, 0.0f);
    if (writeH) hout[(size_t)n * 64 + f] = v;
    int g = batch[n];
    if (g != curg) {
      if (curg >= 0) atomicAdd(&pool[curg * 64 + f], accum);
      curg = g;
      accum = v;
    } else {
      accum += v;
    }
  }
  if (curg >= 0) atomicAdd(&pool[curg * 64 + f], accum);
}

// all 6 prediction heads + L2 normalize; one wave per graph
__global__ __launch_bounds__(64) void prednorm_k(const float* __restrict__ pool0,
    const float* __restrict__ pools, const float* __restrict__ pw0,
    const float* __restrict__ pb0, const float* __restrict__ pwr,
    const float* __restrict__ pbr, float* __restrict__ out, int G) {
  int g = blockIdx.x;
  int j = threadIdx.x;
  float acc = 0.0f;
  if (j < 32) {
    acc = pb0[j];
    for (int k = 0; k < 65; k++) acc += pool0[g * 72 + k] * pw0[k * 32 + j];
    for (int l = 0; l < 5; l++) {
      acc += pbr[l * 32 + j];
      const float* pl = pools + (size_t)l * G * 64 + (size_t)g * 64;
      const float* wl = pwr + (size_t)l * 64 * 32;
      for (int k = 0; k < 64; k++) acc += pl[k] * wl[k * 32 + j];
    }
  }
  float s = acc * acc;
  for (int o = 16; o > 0; o >>= 1) s += __shfl_xor(s, o);
  float nrm = fmaxf(sqrtf(s), 1e-5f);
  if (j < 32) out[g * 32 + j] = acc / nrm;
}

extern "C" void kernel_launch(void* const* d_in, const int* in_sizes, int n_in,
                              void* d_out, int out_size, void* d_ws, size_t ws_size,
                              hipStream_t stream) {
  (void)n_in; (void)out_size; (void)ws_size;
  const float* x          = (const float*)d_in[0];
  const int*   edge_index = (const int*)d_in[1];
  const int*   batch      = (const int*)d_in[2];
  const int*   root       = (const int*)d_in[3];
  const float* deg_table  = (const float*)d_in[4];
  const float* w1_0       = (const float*)d_in[5];
  const float* b1_0       = (const float*)d_in[6];
  const float* w2_0       = (const float*)d_in[7];
  const float* b2_0       = (const float*)d_in[8];
  const float* w1_rest    = (const float*)d_in[9];
  const float* b1_rest    = (const float*)d_in[10];
  const float* w2_rest    = (const float*)d_in[11];
  const float* b2_rest    = (const float*)d_in[12];
  const float* bn_gamma   = (const float*)d_in[13];
  const float* bn_beta    = (const float*)d_in[14];
  const float* pred_w0    = (const float*)d_in[15];
  const float* pred_b0    = (const float*)d_in[16];
  const float* pred_w_rest = (const float*)d_in[17];
  const float* pred_b_rest = (const float*)d_in[18];

  const int N = in_sizes[0] / 32;
  const int E = in_sizes[1] / 2;
  const int G = in_sizes[3];
  const int* src = edge_index;
  const int* dst = edge_index + E;
  const float invN = 1.0f / N;

  // ---- workspace carve-up (256B aligned) ----
  char* w = (char*)d_ws;
  auto alloc = [&](size_t bytes) {
    char* p = w;
    w += (bytes + 255) & ~(size_t)255;
    return p;
  };
  int* d_deg  = (int*)alloc((size_t)N * 4);
  int* d_egof = (int*)alloc((size_t)N * 4);
  int* d_cnt  = (int*)alloc((size_t)N * 4);
  int* d_cur  = (int*)alloc((size_t)N * 4);
  char* zero_int_end = w;
  int* d_off  = (int*)alloc((size_t)(N + 1) * 4);
  int* d_bsum = (int*)alloc(256 * 4);
  int* d_csr  = (int*)alloc((size_t)E * 4);
  float* fsums  = (float*)alloc(15 * 128 * 4);
  float* fpool  = (float*)alloc((size_t)(G * 72 + 5 * G * 64) * 4);
  char* zero_f_end = w;
  float* fh0  = (float*)alloc((size_t)N * 72 * 4);
  float* fB1  = (float*)alloc((size_t)N * 72 * 4);
  float* fB2  = (float*)alloc((size_t)N * 64 * 4);
  float* fB3  = (float*)alloc((size_t)N * 64 * 4);

  hipMemsetAsync(d_deg, 0, (size_t)(zero_int_end - (char*)d_deg), stream);
  hipMemsetAsync(fsums, 0, (size_t)(zero_f_end - (char*)fsums), stream);

  const int ebl = (E + 255) / 256;
  const int nb  = (N + 255) / 256;       // node blocks (N<=65536 assumed)
  const int nwb = (N * 64 + 255) / 256;  // thread per (node,feature)

  count_k<<<ebl, 256, 0, stream>>>(src, dst, d_deg, d_cnt, E);
  scan1_k<<<nb, 256, 0, stream>>>(d_cnt, d_off, d_bsum, N);
  scan2_k<<<1, 256, 0, stream>>>(d_bsum, nb);
  scan3_k<<<nb, 256, 0, stream>>>(d_off, d_bsum, N);
  fill_k<<<ebl, 256, 0, stream>>>(src, dst, d_off, d_cur, d_csr, E);
  root_k<<<1, 256, 0, stream>>>(root, d_egof, G);
  h0_k<<<nb, 256, 0, stream>>>(x, deg_table, d_deg, d_egof, batch, fh0, fpool, N);

  float* pools = fpool + G * 72;
  const float* hcur = fh0;
  for (int l = 0; l < 5; l++) {
    float* zb  = fB1;                          // z = h+agg, then reused as z2
    float* z1b = (l % 2 == 0) ? fB2 : fB3;     // z1, then reused as h_out
    if (l == 0) aggregate_k<65, 72><<<nwb, 256, 0, stream>>>(hcur, d_off, d_csr, zb, N);
    else        aggregate_k<64, 64><<<nwb, 256, 0, stream>>>(hcur, d_off, d_csr, zb, N);

    const float* w1 = (l == 0) ? w1_0 : w1_rest + (size_t)(l - 1) * 64 * 64;
    const float* b1 = (l == 0) ? b1_0 : b1_rest + (size_t)(l - 1) * 64;
    const float* w2 = (l == 0) ? w2_0 : w2_rest + (size_t)(l - 1) * 64 * 64;
    const float* b2 = (l == 0) ? b2_0 : b2_rest + (size_t)(l - 1) * 64;
    float* sums0 = fsums + (l * 3 + 0) * 128;
    float* sums1 = fsums + (l * 3 + 1) * 128;
    float* sums2 = fsums + (l * 3 + 2) * 128;
    const float* g0 = bn_gamma + (l * 3 + 0) * 64;
    const float* be0 = bn_beta + (l * 3 + 0) * 64;
    const float* g1 = bn_gamma + (l * 3 + 1) * 64;
    const float* be1 = bn_beta + (l * 3 + 1) * 64;
    const float* g2 = bn_gamma + (l * 3 + 2) * 64;
    const float* be2 = bn_beta + (l * 3 + 2) * 64;

    if (l == 0) gemm_k<65, false><<<nb, 256, 0, stream>>>(zb, 72, w1, b1, nullptr, nullptr, nullptr, invN, z1b, N);
    else        gemm_k<64, false><<<nb, 256, 0, stream>>>(zb, 64, w1, b1, nullptr, nullptr, nullptr, invN, z1b, N);
    stats_plain_k<<<256, 256, 0, stream>>>(z1b, sums0, N);
    gemm_k<64, true><<<nb, 256, 0, stream>>>(z1b, 64, w2, b2, sums0, g0, be0, invN, zb, N);
    stats_plain_k<<<256, 256, 0, stream>>>(zb, sums1, N);
    stats_bn_k<<<256, 256, 0, stream>>>(zb, sums1, g1, be1, invN, sums2, N);

    float* pool_l = pools + (size_t)l * G * 64;
    apply_k<<<nb, 256, 0, stream>>>(zb, sums1, g1, be1, sums2, g2, be2, invN,
                                    batch, z1b, pool_l, N, (l < 4) ? 1 : 0);
    hcur = z1b;
  }
  prednorm_k<<<G, 64, 0, stream>>>(fpool, pools, pred_w0, pred_b0,
                                   pred_w_rest, pred_b_rest, (float*)d_out, G);
}

// Round 4
// 875.056 us; speedup vs baseline: 1.4094x; 1.2261x over previous
//
#include <hip/hip_runtime.h>

#define PAD 8      // counters padded to PAD ints (line-contention relief)
#define NREP 16    // replicated stat accumulators

// ---------------- CSR build ----------------
__global__ __launch_bounds__(256) void count_k(const int* __restrict__ src,
    const int* __restrict__ dst, int* __restrict__ deg, int* __restrict__ cnt, int E) {
  int e = blockIdx.x * 256 + threadIdx.x;
  if (e < E) {
    atomicAdd(&deg[src[e] * PAD], 1);
    atomicAdd(&cnt[dst[e] * PAD], 1);
  }
}

__global__ __launch_bounds__(256) void scan1_k(const int* __restrict__ cnt,
    int* __restrict__ off, int* __restrict__ bsum, int N) {
  __shared__ int s[256];
  int t = threadIdx.x;
  int i = blockIdx.x * 256 + t;
  int c = (i < N) ? cnt[i * PAD] : 0;
  s[t] = c;
  __syncthreads();
  for (int d = 1; d < 256; d <<= 1) {
    int v = (t >= d) ? s[t - d] : 0;
    __syncthreads();
    s[t] += v;
    __syncthreads();
  }
  if (i < N) off[i + 1] = s[t];
  if (t == 255) bsum[blockIdx.x] = s[255];
}

__global__ __launch_bounds__(256) void scan2_k(int* __restrict__ bsum, int NB) {
  __shared__ int s[256];
  int t = threadIdx.x;
  int c = (t < NB) ? bsum[t] : 0;
  s[t] = c;
  __syncthreads();
  for (int d = 1; d < 256; d <<= 1) {
    int v = (t >= d) ? s[t - d] : 0;
    __syncthreads();
    s[t] += v;
    __syncthreads();
  }
  if (t < NB) bsum[t] = s[t] - c;  // exclusive
}

__global__ __launch_bounds__(256) void scan3_k(int* __restrict__ off,
    const int* __restrict__ bsum, int N) {
  int i = blockIdx.x * 256 + threadIdx.x;
  if (i < N) off[i + 1] += bsum[blockIdx.x];
  if (i == 0) off[0] = 0;
}

// fill using atomicSub on cnt (cnt is dead after scan): first edge lands at off[d].
__global__ __launch_bounds__(256) void fill_k(const int* __restrict__ src,
    const int* __restrict__ dst, const int* __restrict__ off,
    int* __restrict__ cnt, int* __restrict__ csr, int E) {
  int e = blockIdx.x * 256 + threadIdx.x;
  if (e < E) {
    int d = dst[e];
    int old = atomicSub(&cnt[d * PAD], 1);
    csr[off[d + 1] - old] = src[e];
  }
}

__global__ void root_k(const int* __restrict__ root, int* __restrict__ egof, int G) {
  int g = threadIdx.x;
  if (g < G) egof[root[g]] = 1;
}

// h0 = [x | deg_table[min(deg,128)] | ego], row stride 72; segmented pool into pool0.
__global__ __launch_bounds__(256) void h0_k(const float* __restrict__ x,
    const float* __restrict__ deg_table, const int* __restrict__ deg,
    const int* __restrict__ egof, const int* __restrict__ batch,
    float* __restrict__ h0, float* __restrict__ pool0, int N) {
  int w = threadIdx.x >> 6, f = threadIdx.x & 63;
  int base = blockIdx.x * 256;
  int end = min(base + 256, N);
  float accum = 0.0f, accum64 = 0.0f;
  int curg = -1;
  for (int n0 = base + w; n0 < end; n0 += 4) {
    int n = __builtin_amdgcn_readfirstlane(n0);
    float v;
    if (f < 32) {
      v = x[n * 32 + f];
    } else {
      int d = deg[n * PAD];
      if (d > 128) d = 128;
      v = deg_table[d * 32 + (f - 32)];
    }
    h0[(size_t)n * 72 + f] = v;
    float e = 0.0f;
    if (f == 0) {
      e = egof[n] ? 1.0f : 0.0f;
      h0[(size_t)n * 72 + 64] = e;
    }
    int g = batch[n];
    if (g != curg) {
      if (curg >= 0) {
        atomicAdd(&pool0[curg * 72 + f], accum);
        if (f == 0 && accum64 != 0.0f) atomicAdd(&pool0[curg * 72 + 64], accum64);
      }
      curg = g;
      accum = v;
      accum64 = e;
    } else {
      accum += v;
      accum64 += e;
    }
  }
  if (curg >= 0) {
    atomicAdd(&pool0[curg * 72 + f], accum);
    if (f == 0 && accum64 != 0.0f) atomicAdd(&pool0[curg * 72 + 64], accum64);
  }
}

// ---------------- layer1: agg + GEMM1 + sums0, wave-per-node ----------------
// Block-uniform trip count; LDS staging bracketed by __syncthreads().
template <int FEATS, int STRIDE>
__global__ __launch_bounds__(256) void layer1_k(const float* __restrict__ h,
    const int* __restrict__ off, const int* __restrict__ csr,
    const float* __restrict__ W1, const float* __restrict__ B1,
    float* __restrict__ z1, float* __restrict__ sums, int N) {
  __shared__ float zsh[4 * 80];
  __shared__ float ls[256], lq[256];
  const int t = threadIdx.x;
  const int w = t >> 6, lane = t & 63;
  float wcol[64];  // W1 column `lane`, resident in VGPRs
#pragma unroll
  for (int k = 0; k < 64; k++) wcol[k] = W1[k * 64 + lane];
  float wc64 = 0.0f;
  if (FEATS == 65) wc64 = W1[64 * 64 + lane];
  const float bj = B1[lane];
  float* zs = zsh + w * 80;
  float s = 0.0f, q = 0.0f;
  const int step = gridDim.x * 4;
  for (int n0 = blockIdx.x * 4; n0 < N; n0 += step) {
    const int n = n0 + w;
    const bool act = (n < N);
    float z = 0.0f, z64 = 0.0f;
    if (act) {
      const float* row = h + (size_t)n * STRIDE;
      z = row[lane];
      if (FEATS == 65) { if (lane == 0) z64 = row[64]; }
      int k0 = off[n], k1 = off[n + 1];
      int k = k0;
      for (; k + 4 <= k1; k += 4) {
        int i0 = csr[k], i1 = csr[k + 1], i2 = csr[k + 2], i3 = csr[k + 3];
        const float* r0 = h + (size_t)i0 * STRIDE;
        const float* r1 = h + (size_t)i1 * STRIDE;
        const float* r2 = h + (size_t)i2 * STRIDE;
        const float* r3 = h + (size_t)i3 * STRIDE;
        float v0 = r0[lane], v1 = r1[lane], v2 = r2[lane], v3 = r3[lane];
        if (FEATS == 65) { if (lane == 0) z64 += r0[64] + r1[64] + r2[64] + r3[64]; }
        z += v0; z += v1; z += v2; z += v3;
      }
      for (; k < k1; k++) {
        const float* r0 = h + (size_t)csr[k] * STRIDE;
        z += r0[lane];
        if (FEATS == 65) { if (lane == 0) z64 += r0[64]; }
      }
    }
    __syncthreads();
    if (act) {
      zs[lane] = z;
      if (FEATS == 65) { if (lane == 0) zs[64] = z64; }
    }
    __syncthreads();
    if (act) {
      float a0 = bj, a1 = 0.0f, a2 = 0.0f, a3 = 0.0f;
#pragma unroll
      for (int k2 = 0; k2 < 64; k2 += 4) {
        a0 += zs[k2] * wcol[k2];
        a1 += zs[k2 + 1] * wcol[k2 + 1];
        a2 += zs[k2 + 2] * wcol[k2 + 2];
        a3 += zs[k2 + 3] * wcol[k2 + 3];
      }
      if (FEATS == 65) a0 += zs[64] * wc64;
      float acc = (a0 + a1) + (a2 + a3);
      z1[(size_t)n * 64 + lane] = acc;
      s += acc;
      q += acc * acc;
    }
  }
  ls[t] = s; lq[t] = q;
  __syncthreads();
  if (t < 64) {
    float a = ls[t] + ls[64 + t] + ls[128 + t] + ls[192 + t];
    atomicAdd(&sums[(blockIdx.x & (NREP - 1)) * 128 + t], a);
  } else if (t < 128) {
    int f = t - 64;
    float a = lq[f] + lq[64 + f] + lq[128 + f] + lq[192 + f];
    atomicAdd(&sums[(blockIdx.x & (NREP - 1)) * 128 + 64 + f], a);
  }
}

// ---------------- layer2: BN0+ReLU + GEMM2 + sums1, wave-per-node ----------------
__global__ __launch_bounds__(256) void layer2_k(const float* __restrict__ z1,
    const float* __restrict__ W2, const float* __restrict__ B2,
    const float* __restrict__ sums0, const float* __restrict__ g0,
    const float* __restrict__ be0, float invN,
    float* __restrict__ z2, float* __restrict__ sums1, int N) {
  __shared__ float zsh[4 * 64];
  __shared__ float redu[128];
  __shared__ float scs[64], shs[64];
  __shared__ float ls[256], lq[256];
  const int t = threadIdx.x;
  if (t < 128) {
    float a = 0.0f;
#pragma unroll
    for (int b = 0; b < NREP; b++) a += sums0[b * 128 + t];
    redu[t] = a;
  }
  __syncthreads();
  if (t < 64) {
    float m = redu[t] * invN;
    float var = redu[64 + t] * invN - m * m;
    float sc = g0[t] * rsqrtf(var + 1e-5f);
    scs[t] = sc;
    shs[t] = be0[t] - m * sc;
  }
  __syncthreads();
  const int w = t >> 6, lane = t & 63;
  const float sc = scs[lane], sh = shs[lane];
  float wcol[64];
#pragma unroll
  for (int k = 0; k < 64; k++) wcol[k] = W2[k * 64 + lane];
  const float bj = B2[lane];
  float* zs = zsh + w * 64;
  float s = 0.0f, q = 0.0f;
  const int step = gridDim.x * 4;
  for (int n0 = blockIdx.x * 4; n0 < N; n0 += step) {
    const int n = n0 + w;
    const bool act = (n < N);
    float v = 0.0f;
    if (act) {
      v = z1[(size_t)n * 64 + lane];
      v = fmaxf(v * sc + sh, 0.0f);
    }
    __syncthreads();
    if (act) zs[lane] = v;
    __syncthreads();
    if (act) {
      float a0 = bj, a1 = 0.0f, a2 = 0.0f, a3 = 0.0f;
#pragma unroll
      for (int k2 = 0; k2 < 64; k2 += 4) {
        a0 += zs[k2] * wcol[k2];
        a1 += zs[k2 + 1] * wcol[k2 + 1];
        a2 += zs[k2 + 2] * wcol[k2 + 2];
        a3 += zs[k2 + 3] * wcol[k2 + 3];
      }
      float acc = (a0 + a1) + (a2 + a3);
      z2[(size_t)n * 64 + lane] = acc;
      s += acc;
      q += acc * acc;
    }
  }
  ls[t] = s; lq[t] = q;
  __syncthreads();
  if (t < 64) {
    float a = ls[t] + ls[64 + t] + ls[128 + t] + ls[192 + t];
    atomicAdd(&sums1[(blockIdx.x & (NREP - 1)) * 128 + t], a);
  } else if (t < 128) {
    int f = t - 64;
    float a = lq[f] + lq[64 + f] + lq[128 + f] + lq[192 + f];
    atomicAdd(&sums1[(blockIdx.x & (NREP - 1)) * 128 + 64 + f], a);
  }
}

// ---------------- stats of relu(bn1(z2)) -> sums2 ----------------
__global__ __launch_bounds__(256) void statsbn_k(const float* __restrict__ z2,
    const float* __restrict__ sums1, const float* __restrict__ g1,
    const float* __restrict__ be1, float invN, float* __restrict__ sums2, int N) {
  __shared__ float redu[128];
  __shared__ float scs[64], shs[64];
  __shared__ float ls[256], lq[256];
  int t = threadIdx.x;
  if (t < 128) {
    float a = 0.0f;
#pragma unroll
    for (int b = 0; b < NREP; b++) a += sums1[b * 128 + t];
    redu[t] = a;
  }
  __syncthreads();
  if (t < 64) {
    float m = redu[t] * invN;
    float var = redu[64 + t] * invN - m * m;
    float sc = g1[t] * rsqrtf(var + 1e-5f);
    scs[t] = sc;
    shs[t] = be1[t] - m * sc;
  }
  __syncthreads();
  int f = t & 63, r = t >> 6;
  float sc = scs[f], sh = shs[f];
  float s = 0.0f, q = 0.0f;
  for (int n = blockIdx.x * 4 + r; n < N; n += gridDim.x * 4) {
    float v = z2[(size_t)n * 64 + f];
    v = fmaxf(v * sc + sh, 0.0f);
    s += v;
    q += v * v;
  }
  ls[t] = s; lq[t] = q;
  __syncthreads();
  if (t < 64) {
    float a = ls[t] + ls[64 + t] + ls[128 + t] + ls[192 + t];
    atomicAdd(&sums2[(blockIdx.x & (NREP - 1)) * 128 + t], a);
  } else if (t < 128) {
    int ff = t - 64;
    float a = lq[ff] + lq[64 + ff] + lq[128 + ff] + lq[192 + ff];
    atomicAdd(&sums2[(blockIdx.x & (NREP - 1)) * 128 + 64 + ff], a);
  }
}

// ---------------- h_out = relu(bn2(relu(bn1(z2)))) + segmented pool ----------------
__global__ __launch_bounds__(256) void apply_k(const float* __restrict__ z2,
    const float* __restrict__ sums1, const float* __restrict__ g1, const float* __restrict__ be1,
    const float* __restrict__ sums2, const float* __restrict__ g2, const float* __restrict__ be2,
    float invN, const int* __restrict__ batch, float* __restrict__ hout,
    float* __restrict__ pool, int N, int writeH) {
  __shared__ float red1[128], red2[128];
  __shared__ float sc1s[64], sh1s[64], sc2s[64], sh2s[64];
  int t = threadIdx.x;
  if (t < 128) {
    float a = 0.0f, c = 0.0f;
#pragma unroll
    for (int b = 0; b < NREP; b++) { a += sums1[b * 128 + t]; c += sums2[b * 128 + t]; }
    red1[t] = a;
    red2[t] = c;
  }
  __syncthreads();
  if (t < 64) {
    float m = red1[t] * invN;
    float var = red1[64 + t] * invN - m * m;
    float sc = g1[t] * rsqrtf(var + 1e-5f);
    sc1s[t] = sc;
    sh1s[t] = be1[t] - m * sc;
    m = red2[t] * invN;
    var = red2[64 + t] * invN - m * m;
    sc = g2[t] * rsqrtf(var + 1e-5f);
    sc2s[t] = sc;
    sh2s[t] = be2[t] - m * sc;
  }
  __syncthreads();
  int w = t >> 6, f = t & 63;
  float sc1 = sc1s[f], sh1 = sh1s[f], sc2 = sc2s[f], sh2 = sh2s[f];
  int base = blockIdx.x * 256;
  int end = min(base + 256, N);
  float accum = 0.0f;
  int curg = -1;
  for (int n0 = base + w; n0 < end; n0 += 4) {
    int n = __builtin_amdgcn_readfirstlane(n0);
    float v = z2[(size_t)n * 64 + f];
    v = fmaxf(v * sc1 + sh1, 0.0f);
    v = fmaxf(v * sc2 + sh2, 0.0f);
    if (writeH) hout[(size_t)n * 64 + f] = v;
    int g = batch[n];
    if (g != curg) {
      if (curg >= 0) atomicAdd(&pool[curg * 64 + f], accum);
      curg = g;
      accum = v;
    } else {
      accum += v;
    }
  }
  if (curg >= 0) atomicAdd(&pool[curg * 64 + f], accum);
}

// ---------------- all 6 prediction heads + L2 normalize; one wave per graph ----------------
__global__ __launch_bounds__(64) void prednorm_k(const float* __restrict__ pool0,
    const float* __restrict__ pools, const float* __restrict__ pw0,
    const float* __restrict__ pb0, const float* __restrict__ pwr,
    const float* __restrict__ pbr, float* __restrict__ out, int G) {
  int g = blockIdx.x;
  int j = threadIdx.x;
  float acc = 0.0f;
  if (j < 32) {
    acc = pb0[j];
    for (int k = 0; k < 65; k++) acc += pool0[g * 72 + k] * pw0[k * 32 + j];
    for (int l = 0; l < 5; l++) {
      acc += pbr[l * 32 + j];
      const float* pl = pools + (size_t)l * G * 64 + (size_t)g * 64;
      const float* wl = pwr + (size_t)l * 64 * 32;
      for (int k = 0; k < 64; k++) acc += pl[k] * wl[k * 32 + j];
    }
  }
  float s = acc * acc;
  for (int o = 16; o > 0; o >>= 1) s += __shfl_xor(s, o);
  float nrm = fmaxf(sqrtf(s), 1e-5f);
  if (j < 32) out[g * 32 + j] = acc / nrm;
}

extern "C" void kernel_launch(void* const* d_in, const int* in_sizes, int n_in,
                              void* d_out, int out_size, void* d_ws, size_t ws_size,
                              hipStream_t stream) {
  (void)n_in; (void)out_size; (void)ws_size;
  const float* x          = (const float*)d_in[0];
  const int*   edge_index = (const int*)d_in[1];
  const int*   batch      = (const int*)d_in[2];
  const int*   root       = (const int*)d_in[3];
  const float* deg_table  = (const float*)d_in[4];
  const float* w1_0       = (const float*)d_in[5];
  const float* b1_0       = (const float*)d_in[6];
  const float* w2_0       = (const float*)d_in[7];
  const float* b2_0       = (const float*)d_in[8];
  const float* w1_rest    = (const float*)d_in[9];
  const float* b1_rest    = (const float*)d_in[10];
  const float* w2_rest    = (const float*)d_in[11];
  const float* b2_rest    = (const float*)d_in[12];
  const float* bn_gamma   = (const float*)d_in[13];
  const float* bn_beta    = (const float*)d_in[14];
  const float* pred_w0    = (const float*)d_in[15];
  const float* pred_b0    = (const float*)d_in[16];
  const float* pred_w_rest = (const float*)d_in[17];
  const float* pred_b_rest = (const float*)d_in[18];

  const int N = in_sizes[0] / 32;
  const int E = in_sizes[1] / 2;
  const int G = in_sizes[3];
  const int* src = edge_index;
  const int* dst = edge_index + E;
  const float invN = 1.0f / N;

  // ---- workspace carve-up (256B aligned) ----
  char* w = (char*)d_ws;
  auto alloc = [&](size_t bytes) {
    char* p = w;
    w += (bytes + 255) & ~(size_t)255;
    return p;
  };
  int* d_deg  = (int*)alloc((size_t)N * PAD * 4);
  int* d_cnt  = (int*)alloc((size_t)N * PAD * 4);
  int* d_egof = (int*)alloc((size_t)N * 4);
  char* zero_int_end = w;
  int* d_off  = (int*)alloc((size_t)(N + 1) * 4);
  int* d_bsum = (int*)alloc(256 * 4);
  int* d_csr  = (int*)alloc((size_t)E * 4);
  float* fsums = (float*)alloc((size_t)15 * NREP * 128 * 4);
  float* fpool = (float*)alloc((size_t)(G * 72 + 5 * G * 64) * 4);
  char* zero_f_end = w;
  float* fh0 = (float*)alloc((size_t)N * 72 * 4);
  float* fB1 = (float*)alloc((size_t)N * 64 * 4);  // z1
  float* fB2 = (float*)alloc((size_t)N * 64 * 4);  // z2
  float* fB3 = (float*)alloc((size_t)N * 64 * 4);  // h ping-pong with fh0

  hipMemsetAsync(d_deg, 0, (size_t)(zero_int_end - (char*)d_deg), stream);
  hipMemsetAsync(fsums, 0, (size_t)(zero_f_end - (char*)fsums), stream);

  const int ebl = (E + 255) / 256;
  const int nb  = (N + 255) / 256;

  count_k<<<ebl, 256, 0, stream>>>(src, dst, d_deg, d_cnt, E);
  scan1_k<<<nb, 256, 0, stream>>>(d_cnt, d_off, d_bsum, N);
  scan2_k<<<1, 256, 0, stream>>>(d_bsum, nb);
  scan3_k<<<nb, 256, 0, stream>>>(d_off, d_bsum, N);
  fill_k<<<ebl, 256, 0, stream>>>(src, dst, d_off, d_cnt, d_csr, E);
  root_k<<<1, 256, 0, stream>>>(root, d_egof, G);
  h0_k<<<nb, 256, 0, stream>>>(x, deg_table, d_deg, d_egof, batch, fh0, fpool, N);

  float* pools = fpool + G * 72;
  const float* hcur = fh0;
  float* hnext = fB3;
  for (int l = 0; l < 5; l++) {
    const float* w1 = (l == 0) ? w1_0 : w1_rest + (size_t)(l - 1) * 64 * 64;
    const float* b1 = (l == 0) ? b1_0 : b1_rest + (size_t)(l - 1) * 64;
    const float* w2 = (l == 0) ? w2_0 : w2_rest + (size_t)(l - 1) * 64 * 64;
    const float* b2 = (l == 0) ? b2_0 : b2_rest + (size_t)(l - 1) * 64;
    float* sums0 = fsums + (size_t)(l * 3 + 0) * NREP * 128;
    float* sums1 = fsums + (size_t)(l * 3 + 1) * NREP * 128;
    float* sums2 = fsums + (size_t)(l * 3 + 2) * NREP * 128;
    const float* g0 = bn_gamma + (l * 3 + 0) * 64;
    const float* be0 = bn_beta + (l * 3 + 0) * 64;
    const float* g1 = bn_gamma + (l * 3 + 1) * 64;
    const float* be1 = bn_beta + (l * 3 + 1) * 64;
    const float* g2 = bn_gamma + (l * 3 + 2) * 64;
    const float* be2 = bn_beta + (l * 3 + 2) * 64;

    if (l == 0)
      layer1_k<65, 72><<<1024, 256, 0, stream>>>(hcur, d_off, d_csr, w1, b1, fB1, sums0, N);
    else
      layer1_k<64, 64><<<1024, 256, 0, stream>>>(hcur, d_off, d_csr, w1, b1, fB1, sums0, N);
    layer2_k<<<1024, 256, 0, stream>>>(fB1, w2, b2, sums0, g0, be0, invN, fB2, sums1, N);
    statsbn_k<<<512, 256, 0, stream>>>(fB2, sums1, g1, be1, invN, sums2, N);
    float* pool_l = pools + (size_t)l * G * 64;
    apply_k<<<nb, 256, 0, stream>>>(fB2, sums1, g1, be1, sums2, g2, be2, invN,
                                    batch, hnext, pool_l, N, (l < 4) ? 1 : 0);
    const float* tmp = hcur;
    hcur = hnext;
    hnext = (float*)tmp;
  }
  prednorm_k<<<G, 64, 0, stream>>>(fpool, pools, pred_w0, pred_b0,
                                   pred_w_rest, pred_b_rest, (float*)d_out, G);
}

// Round 5
// 800.201 us; speedup vs baseline: 1.5412x; 1.0935x over previous
//
#include <hip/hip_runtime.h>

#define PAD 8      // counters padded to PAD ints (line-contention relief)
#define NREP 16    // replicated stat accumulators

// broadcast z from lane l (compile-time l) to all lanes via v_readlane (SGPR)
#define BCAST(v, l) __uint_as_float(__builtin_amdgcn_readlane(__float_as_uint(v), (l)))

// ---------------- CSR build ----------------
__global__ __launch_bounds__(256) void count_k(const int* __restrict__ src,
    const int* __restrict__ dst, int* __restrict__ deg, int* __restrict__ cnt, int E) {
  int e = blockIdx.x * 256 + threadIdx.x;
  if (e < E) {
    atomicAdd(&deg[src[e] * PAD], 1);
    atomicAdd(&cnt[dst[e] * PAD], 1);
  }
}

__global__ __launch_bounds__(256) void scan1_k(const int* __restrict__ cnt,
    int* __restrict__ off, int* __restrict__ bsum, int N) {
  __shared__ int s[256];
  int t = threadIdx.x;
  int i = blockIdx.x * 256 + t;
  int c = (i < N) ? cnt[i * PAD] : 0;
  s[t] = c;
  __syncthreads();
  for (int d = 1; d < 256; d <<= 1) {
    int v = (t >= d) ? s[t - d] : 0;
    __syncthreads();
    s[t] += v;
    __syncthreads();
  }
  if (i < N) off[i + 1] = s[t];
  if (t == 255) bsum[blockIdx.x] = s[255];
}

__global__ __launch_bounds__(256) void scan2_k(int* __restrict__ bsum, int NB) {
  __shared__ int s[256];
  int t = threadIdx.x;
  int c = (t < NB) ? bsum[t] : 0;
  s[t] = c;
  __syncthreads();
  for (int d = 1; d < 256; d <<= 1) {
    int v = (t >= d) ? s[t - d] : 0;
    __syncthreads();
    s[t] += v;
    __syncthreads();
  }
  if (t < NB) bsum[t] = s[t] - c;  // exclusive
}

__global__ __launch_bounds__(256) void scan3_k(int* __restrict__ off,
    const int* __restrict__ bsum, int N) {
  int i = blockIdx.x * 256 + threadIdx.x;
  if (i < N) off[i + 1] += bsum[blockIdx.x];
  if (i == 0) off[0] = 0;
}

// fill using atomicSub on cnt (cnt is dead after scan): first edge lands at off[d].
__global__ __launch_bounds__(256) void fill_k(const int* __restrict__ src,
    const int* __restrict__ dst, const int* __restrict__ off,
    int* __restrict__ cnt, int* __restrict__ csr, int E) {
  int e = blockIdx.x * 256 + threadIdx.x;
  if (e < E) {
    int d = dst[e];
    int old = atomicSub(&cnt[d * PAD], 1);
    csr[off[d + 1] - old] = src[e];
  }
}

__global__ void root_k(const int* __restrict__ root, int* __restrict__ egof, int G) {
  int g = threadIdx.x;
  if (g < G) egof[root[g]] = 1;
}

// h0 = [x | deg_table[min(deg,128)] | ego], row stride 72; segmented pool into pool0.
__global__ __launch_bounds__(256) void h0_k(const float* __restrict__ x,
    const float* __restrict__ deg_table, const int* __restrict__ deg,
    const int* __restrict__ egof, const int* __restrict__ batch,
    float* __restrict__ h0, float* __restrict__ pool0, int N) {
  int w = threadIdx.x >> 6, f = threadIdx.x & 63;
  int base = blockIdx.x * 256;
  int end = min(base + 256, N);
  float accum = 0.0f, accum64 = 0.0f;
  int curg = -1;
  for (int n0 = base + w; n0 < end; n0 += 4) {
    int n = __builtin_amdgcn_readfirstlane(n0);
    float v;
    if (f < 32) {
      v = x[n * 32 + f];
    } else {
      int d = deg[n * PAD];
      if (d > 128) d = 128;
      v = deg_table[d * 32 + (f - 32)];
    }
    h0[(size_t)n * 72 + f] = v;
    float e = 0.0f;
    if (f == 0) {
      e = egof[n] ? 1.0f : 0.0f;
      h0[(size_t)n * 72 + 64] = e;
    }
    int g = batch[n];
    if (g != curg) {
      if (curg >= 0) {
        atomicAdd(&pool0[curg * 72 + f], accum);
        if (f == 0 && accum64 != 0.0f) atomicAdd(&pool0[curg * 72 + 64], accum64);
      }
      curg = g;
      accum = v;
      accum64 = e;
    } else {
      accum += v;
      accum64 += e;
    }
  }
  if (curg >= 0) {
    atomicAdd(&pool0[curg * 72 + f], accum);
    if (f == 0 && accum64 != 0.0f) atomicAdd(&pool0[curg * 72 + 64], accum64);
  }
}

// ---------------- layer1: agg + GEMM1 + sums0, wave-per-node, barrier-free ----------------
// GEMM broadcast via v_readlane (no LDS z staging, no per-iteration barriers).
template <int FEATS, int STRIDE>
__global__ __launch_bounds__(256) void layer1_k(const float* __restrict__ h,
    const int* __restrict__ off, const int* __restrict__ csr,
    const float* __restrict__ W1, const float* __restrict__ B1,
    float* __restrict__ z1, float* __restrict__ sums, int N) {
  __shared__ float Wsh[FEATS * 64];
  __shared__ float ls[256], lq[256];
  const int t = threadIdx.x;
  for (int i = t; i < FEATS * 64; i += 256) Wsh[i] = W1[i];
  __syncthreads();
  const int w = t >> 6, lane = t & 63;
  const float bj = B1[lane];
  float s = 0.0f, q = 0.0f;
  const int step = gridDim.x * 4;
  for (int n0 = blockIdx.x * 4 + w; n0 < N; n0 += step) {
    const int n = __builtin_amdgcn_readfirstlane(n0);
    const float* row = h + (size_t)n * STRIDE;
    float z = row[lane];
    float z64 = 0.0f;
    if (FEATS == 65) { if (lane == 0) z64 = row[64]; }
    const int k1 = off[n + 1];
    int k = off[n];
    for (; k + 8 <= k1; k += 8) {
      int i0 = csr[k], i1 = csr[k + 1], i2 = csr[k + 2], i3 = csr[k + 3];
      int i4 = csr[k + 4], i5 = csr[k + 5], i6 = csr[k + 6], i7 = csr[k + 7];
      const float* r0 = h + (size_t)i0 * STRIDE;
      const float* r1 = h + (size_t)i1 * STRIDE;
      const float* r2 = h + (size_t)i2 * STRIDE;
      const float* r3 = h + (size_t)i3 * STRIDE;
      const float* r4 = h + (size_t)i4 * STRIDE;
      const float* r5 = h + (size_t)i5 * STRIDE;
      const float* r6 = h + (size_t)i6 * STRIDE;
      const float* r7 = h + (size_t)i7 * STRIDE;
      float v0 = r0[lane], v1 = r1[lane], v2 = r2[lane], v3 = r3[lane];
      float v4 = r4[lane], v5 = r5[lane], v6 = r6[lane], v7 = r7[lane];
      if (FEATS == 65) {
        if (lane == 0)
          z64 += ((r0[64] + r1[64]) + (r2[64] + r3[64])) +
                 ((r4[64] + r5[64]) + (r6[64] + r7[64]));
      }
      z += ((v0 + v1) + (v2 + v3)) + ((v4 + v5) + (v6 + v7));
    }
    for (; k < k1; k++) {
      const float* r0 = h + (size_t)csr[k] * STRIDE;
      z += r0[lane];
      if (FEATS == 65) { if (lane == 0) z64 += r0[64]; }
    }
    float a0 = bj, a1 = 0.0f, a2 = 0.0f, a3 = 0.0f;
#pragma unroll
    for (int k2 = 0; k2 < 64; k2 += 4) {
      a0 += BCAST(z, k2) * Wsh[k2 * 64 + lane];
      a1 += BCAST(z, k2 + 1) * Wsh[(k2 + 1) * 64 + lane];
      a2 += BCAST(z, k2 + 2) * Wsh[(k2 + 2) * 64 + lane];
      a3 += BCAST(z, k2 + 3) * Wsh[(k2 + 3) * 64 + lane];
    }
    if (FEATS == 65) a0 += BCAST(z64, 0) * Wsh[64 * 64 + lane];
    float acc = (a0 + a1) + (a2 + a3);
    z1[(size_t)n * 64 + lane] = acc;
    s += acc;
    q += acc * acc;
  }
  ls[t] = s; lq[t] = q;
  __syncthreads();
  if (t < 64) {
    float a = ls[t] + ls[64 + t] + ls[128 + t] + ls[192 + t];
    atomicAdd(&sums[(blockIdx.x & (NREP - 1)) * 128 + t], a);
  } else if (t < 128) {
    int f = t - 64;
    float a = lq[f] + lq[64 + f] + lq[128 + f] + lq[192 + f];
    atomicAdd(&sums[(blockIdx.x & (NREP - 1)) * 128 + 64 + f], a);
  }
}

// ---------------- layer2: BN0+ReLU + GEMM2 + sums1, wave-per-node, barrier-free ----------------
__global__ __launch_bounds__(256) void layer2_k(const float* __restrict__ z1,
    const float* __restrict__ W2, const float* __restrict__ B2,
    const float* __restrict__ sums0, const float* __restrict__ g0,
    const float* __restrict__ be0, float invN,
    float* __restrict__ z2, float* __restrict__ sums1, int N) {
  __shared__ float Wsh[64 * 64];
  __shared__ float redu[128];
  __shared__ float scs[64], shs[64];
  __shared__ float ls[256], lq[256];
  const int t = threadIdx.x;
  for (int i = t; i < 64 * 64; i += 256) Wsh[i] = W2[i];
  if (t < 128) {
    float a = 0.0f;
#pragma unroll
    for (int b = 0; b < NREP; b++) a += sums0[b * 128 + t];
    redu[t] = a;
  }
  __syncthreads();
  if (t < 64) {
    float m = redu[t] * invN;
    float var = redu[64 + t] * invN - m * m;
    float sc = g0[t] * rsqrtf(var + 1e-5f);
    scs[t] = sc;
    shs[t] = be0[t] - m * sc;
  }
  __syncthreads();
  const int w = t >> 6, lane = t & 63;
  const float sc = scs[lane], sh = shs[lane];
  const float bj = B2[lane];
  float s = 0.0f, q = 0.0f;
  const int step = gridDim.x * 4;
  for (int n0 = blockIdx.x * 4 + w; n0 < N; n0 += step) {
    const int n = __builtin_amdgcn_readfirstlane(n0);
    float v = z1[(size_t)n * 64 + lane];
    v = fmaxf(v * sc + sh, 0.0f);
    float a0 = bj, a1 = 0.0f, a2 = 0.0f, a3 = 0.0f;
#pragma unroll
    for (int k2 = 0; k2 < 64; k2 += 4) {
      a0 += BCAST(v, k2) * Wsh[k2 * 64 + lane];
      a1 += BCAST(v, k2 + 1) * Wsh[(k2 + 1) * 64 + lane];
      a2 += BCAST(v, k2 + 2) * Wsh[(k2 + 2) * 64 + lane];
      a3 += BCAST(v, k2 + 3) * Wsh[(k2 + 3) * 64 + lane];
    }
    float acc = (a0 + a1) + (a2 + a3);
    z2[(size_t)n * 64 + lane] = acc;
    s += acc;
    q += acc * acc;
  }
  ls[t] = s; lq[t] = q;
  __syncthreads();
  if (t < 64) {
    float a = ls[t] + ls[64 + t] + ls[128 + t] + ls[192 + t];
    atomicAdd(&sums1[(blockIdx.x & (NREP - 1)) * 128 + t], a);
  } else if (t < 128) {
    int f = t - 64;
    float a = lq[f] + lq[64 + f] + lq[128 + f] + lq[192 + f];
    atomicAdd(&sums1[(blockIdx.x & (NREP - 1)) * 128 + 64 + f], a);
  }
}

// ---------------- stats of relu(bn1(z2)) -> sums2 ----------------
__global__ __launch_bounds__(256) void statsbn_k(const float* __restrict__ z2,
    const float* __restrict__ sums1, const float* __restrict__ g1,
    const float* __restrict__ be1, float invN, float* __restrict__ sums2, int N) {
  __shared__ float redu[128];
  __shared__ float scs[64], shs[64];
  __shared__ float ls[256], lq[256];
  int t = threadIdx.x;
  if (t < 128) {
    float a = 0.0f;
#pragma unroll
    for (int b = 0; b < NREP; b++) a += sums1[b * 128 + t];
    redu[t] = a;
  }
  __syncthreads();
  if (t < 64) {
    float m = redu[t] * invN;
    float var = redu[64 + t] * invN - m * m;
    float sc = g1[t] * rsqrtf(var + 1e-5f);
    scs[t] = sc;
    shs[t] = be1[t] - m * sc;
  }
  __syncthreads();
  int f = t & 63, r = t >> 6;
  float sc = scs[f], sh = shs[f];
  float s = 0.0f, q = 0.0f;
  for (int n = blockIdx.x * 4 + r; n < N; n += gridDim.x * 4) {
    float v = z2[(size_t)n * 64 + f];
    v = fmaxf(v * sc + sh, 0.0f);
    s += v;
    q += v * v;
  }
  ls[t] = s; lq[t] = q;
  __syncthreads();
  if (t < 64) {
    float a = ls[t] + ls[64 + t] + ls[128 + t] + ls[192 + t];
    atomicAdd(&sums2[(blockIdx.x & (NREP - 1)) * 128 + t], a);
  } else if (t < 128) {
    int ff = t - 64;
    float a = lq[ff] + lq[64 + ff] + lq[128 + ff] + lq[192 + ff];
    atomicAdd(&sums2[(blockIdx.x & (NREP - 1)) * 128 + 64 + ff], a);
  }
}

// ---------------- h_out = relu(bn2(relu(bn1(z2)))) + segmented pool ----------------
__global__ __launch_bounds__(256) void apply_k(const float* __restrict__ z2,
    const float* __restrict__ sums1, const float* __restrict__ g1, const float* __restrict__ be1,
    const float* __restrict__ sums2, const float* __restrict__ g2, const float* __restrict__ be2,
    float invN, const int* __restrict__ batch, float* __restrict__ hout,
    float* __restrict__ pool, int N, int writeH) {
  __shared__ float red1[128], red2[128];
  __shared__ float sc1s[64], sh1s[64], sc2s[64], sh2s[64];
  int t = threadIdx.x;
  if (t < 128) {
    float a = 0.0f, c = 0.0f;
#pragma unroll
    for (int b = 0; b < NREP; b++) { a += sums1[b * 128 + t]; c += sums2[b * 128 + t]; }
    red1[t] = a;
    red2[t] = c;
  }
  __syncthreads();
  if (t < 64) {
    float m = red1[t] * invN;
    float var = red1[64 + t] * invN - m * m;
    float sc = g1[t] * rsqrtf(var + 1e-5f);
    sc1s[t] = sc;
    sh1s[t] = be1[t] - m * sc;
    m = red2[t] * invN;
    var = red2[64 + t] * invN - m * m;
    sc = g2[t] * rsqrtf(var + 1e-5f);
    sc2s[t] = sc;
    sh2s[t] = be2[t] - m * sc;
  }
  __syncthreads();
  int w = t >> 6, f = t & 63;
  float sc1 = sc1s[f], sh1 = sh1s[f], sc2 = sc2s[f], sh2 = sh2s[f];
  int base = blockIdx.x * 256;
  int end = min(base + 256, N);
  float accum = 0.0f;
  int curg = -1;
  for (int n0 = base + w; n0 < end; n0 += 4) {
    int n = __builtin_amdgcn_readfirstlane(n0);
    float v = z2[(size_t)n * 64 + f];
    v = fmaxf(v * sc1 + sh1, 0.0f);
    v = fmaxf(v * sc2 + sh2, 0.0f);
    if (writeH) hout[(size_t)n * 64 + f] = v;
    int g = batch[n];
    if (g != curg) {
      if (curg >= 0) atomicAdd(&pool[curg * 64 + f], accum);
      curg = g;
      accum = v;
    } else {
      accum += v;
    }
  }
  if (curg >= 0) atomicAdd(&pool[curg * 64 + f], accum);
}

// ---------------- all 6 prediction heads + L2 normalize; one wave per graph ----------------
__global__ __launch_bounds__(64) void prednorm_k(const float* __restrict__ pool0,
    const float* __restrict__ pools, const float* __restrict__ pw0,
    const float* __restrict__ pb0, const float* __restrict__ pwr,
    const float* __restrict__ pbr, float* __restrict__ out, int G) {
  int g = blockIdx.x;
  int j = threadIdx.x;
  float acc = 0.0f;
  if (j < 32) {
    acc = pb0[j];
    for (int k = 0; k < 65; k++) acc += pool0[g * 72 + k] * pw0[k * 32 + j];
    for (int l = 0; l < 5; l++) {
      acc += pbr[l * 32 + j];
      const float* pl = pools + (size_t)l * G * 64 + (size_t)g * 64;
      const float* wl = pwr + (size_t)l * 64 * 32;
      for (int k = 0; k < 64; k++) acc += pl[k] * wl[k * 32 + j];
    }
  }
  float s = acc * acc;
  for (int o = 16; o > 0; o >>= 1) s += __shfl_xor(s, o);
  float nrm = fmaxf(sqrtf(s), 1e-5f);
  if (j < 32) out[g * 32 + j] = acc / nrm;
}

extern "C" void kernel_launch(void* const* d_in, const int* in_sizes, int n_in,
                              void* d_out, int out_size, void* d_ws, size_t ws_size,
                              hipStream_t stream) {
  (void)n_in; (void)out_size; (void)ws_size;
  const float* x          = (const float*)d_in[0];
  const int*   edge_index = (const int*)d_in[1];
  const int*   batch      = (const int*)d_in[2];
  const int*   root       = (const int*)d_in[3];
  const float* deg_table  = (const float*)d_in[4];
  const float* w1_0       = (const float*)d_in[5];
  const float* b1_0       = (const float*)d_in[6];
  const float* w2_0       = (const float*)d_in[7];
  const float* b2_0       = (const float*)d_in[8];
  const float* w1_rest    = (const float*)d_in[9];
  const float* b1_rest    = (const float*)d_in[10];
  const float* w2_rest    = (const float*)d_in[11];
  const float* b2_rest    = (const float*)d_in[12];
  const float* bn_gamma   = (const float*)d_in[13];
  const float* bn_beta    = (const float*)d_in[14];
  const float* pred_w0    = (const float*)d_in[15];
  const float* pred_b0    = (const float*)d_in[16];
  const float* pred_w_rest = (const float*)d_in[17];
  const float* pred_b_rest = (const float*)d_in[18];

  const int N = in_sizes[0] / 32;
  const int E = in_sizes[1] / 2;
  const int G = in_sizes[3];
  const int* src = edge_index;
  const int* dst = edge_index + E;
  const float invN = 1.0f / N;

  // ---- workspace carve-up (256B aligned) ----
  char* w = (char*)d_ws;
  auto alloc = [&](size_t bytes) {
    char* p = w;
    w += (bytes + 255) & ~(size_t)255;
    return p;
  };
  int* d_deg  = (int*)alloc((size_t)N * PAD * 4);
  int* d_cnt  = (int*)alloc((size_t)N * PAD * 4);
  int* d_egof = (int*)alloc((size_t)N * 4);
  char* zero_int_end = w;
  int* d_off  = (int*)alloc((size_t)(N + 1) * 4);
  int* d_bsum = (int*)alloc(256 * 4);
  int* d_csr  = (int*)alloc((size_t)E * 4);
  float* fsums = (float*)alloc((size_t)15 * NREP * 128 * 4);
  float* fpool = (float*)alloc((size_t)(G * 72 + 5 * G * 64) * 4);
  char* zero_f_end = w;
  float* fh0 = (float*)alloc((size_t)N * 72 * 4);
  float* fB1 = (float*)alloc((size_t)N * 64 * 4);  // z1
  float* fB2 = (float*)alloc((size_t)N * 64 * 4);  // z2
  float* fB3 = (float*)alloc((size_t)N * 64 * 4);  // h ping-pong with fh0

  hipMemsetAsync(d_deg, 0, (size_t)(zero_int_end - (char*)d_deg), stream);
  hipMemsetAsync(fsums, 0, (size_t)(zero_f_end - (char*)fsums), stream);

  const int ebl = (E + 255) / 256;
  const int nb  = (N + 255) / 256;

  count_k<<<ebl, 256, 0, stream>>>(src, dst, d_deg, d_cnt, E);
  scan1_k<<<nb, 256, 0, stream>>>(d_cnt, d_off, d_bsum, N);
  scan2_k<<<1, 256, 0, stream>>>(d_bsum, nb);
  scan3_k<<<nb, 256, 0, stream>>>(d_off, d_bsum, N);
  fill_k<<<ebl, 256, 0, stream>>>(src, dst, d_off, d_cnt, d_csr, E);
  root_k<<<1, 256, 0, stream>>>(root, d_egof, G);
  h0_k<<<nb, 256, 0, stream>>>(x, deg_table, d_deg, d_egof, batch, fh0, fpool, N);

  float* pools = fpool + G * 72;
  const float* hcur = fh0;
  float* hnext = fB3;
  for (int l = 0; l < 5; l++) {
    const float* w1 = (l == 0) ? w1_0 : w1_rest + (size_t)(l - 1) * 64 * 64;
    const float* b1 = (l == 0) ? b1_0 : b1_rest + (size_t)(l - 1) * 64;
    const float* w2 = (l == 0) ? w2_0 : w2_rest + (size_t)(l - 1) * 64 * 64;
    const float* b2 = (l == 0) ? b2_0 : b2_rest + (size_t)(l - 1) * 64;
    float* sums0 = fsums + (size_t)(l * 3 + 0) * NREP * 128;
    float* sums1 = fsums + (size_t)(l * 3 + 1) * NREP * 128;
    float* sums2 = fsums + (size_t)(l * 3 + 2) * NREP * 128;
    const float* g0 = bn_gamma + (l * 3 + 0) * 64;
    const float* be0 = bn_beta + (l * 3 + 0) * 64;
    const float* g1 = bn_gamma + (l * 3 + 1) * 64;
    const float* be1 = bn_beta + (l * 3 + 1) * 64;
    const float* g2 = bn_gamma + (l * 3 + 2) * 64;
    const float* be2 = bn_beta + (l * 3 + 2) * 64;

    if (l == 0)
      layer1_k<65, 72><<<2048, 256, 0, stream>>>(hcur, d_off, d_csr, w1, b1, fB1, sums0, N);
    else
      layer1_k<64, 64><<<2048, 256, 0, stream>>>(hcur, d_off, d_csr, w1, b1, fB1, sums0, N);
    layer2_k<<<2048, 256, 0, stream>>>(fB1, w2, b2, sums0, g0, be0, invN, fB2, sums1, N);
    statsbn_k<<<512, 256, 0, stream>>>(fB2, sums1, g1, be1, invN, sums2, N);
    float* pool_l = pools + (size_t)l * G * 64;
    apply_k<<<nb, 256, 0, stream>>>(fB2, sums1, g1, be1, sums2, g2, be2, invN,
                                    batch, hnext, pool_l, N, (l < 4) ? 1 : 0);
    const float* tmp = hcur;
    hcur = hnext;
    hnext = (float*)tmp;
  }
  prednorm_k<<<G, 64, 0, stream>>>(fpool, pools, pred_w0, pred_b0,
                                   pred_w_rest, pred_b_rest, (float*)d_out, G);
}

// Round 6
// 670.755 us; speedup vs baseline: 1.8387x; 1.1930x over previous
//
#include <hip/hip_runtime.h>

#define PAD 8      // counters padded to PAD ints
#define NREP 16    // replicated stat accumulators
#define CHUNK 64   // nodes per block for segmented-pool kernels

// broadcast z from lane l (compile-time l) to all lanes via v_readlane (SGPR)
#define BCAST(v, l) __uint_as_float(__builtin_amdgcn_readlane(__float_as_uint(v), (l)))

// ---------------- CSR build ----------------
__global__ __launch_bounds__(256) void count_k(const int* __restrict__ src,
    const int* __restrict__ dst, int* __restrict__ deg, int* __restrict__ cnt, int E) {
  int e = blockIdx.x * 256 + threadIdx.x;
  if (e < E) {
    atomicAdd(&deg[src[e] * PAD], 1);
    atomicAdd(&cnt[dst[e] * PAD], 1);
  }
}

__global__ __launch_bounds__(256) void scan1_k(const int* __restrict__ cnt,
    int* __restrict__ off, int* __restrict__ bsum, int N) {
  __shared__ int s[256];
  int t = threadIdx.x;
  int i = blockIdx.x * 256 + t;
  int c = (i < N) ? cnt[i * PAD] : 0;
  s[t] = c;
  __syncthreads();
  for (int d = 1; d < 256; d <<= 1) {
    int v = (t >= d) ? s[t - d] : 0;
    __syncthreads();
    s[t] += v;
    __syncthreads();
  }
  if (i < N) off[i + 1] = s[t];
  if (t == 255) bsum[blockIdx.x] = s[255];
}

__global__ __launch_bounds__(256) void scan2_k(int* __restrict__ bsum, int NB) {
  __shared__ int s[256];
  int t = threadIdx.x;
  int c = (t < NB) ? bsum[t] : 0;
  s[t] = c;
  __syncthreads();
  for (int d = 1; d < 256; d <<= 1) {
    int v = (t >= d) ? s[t - d] : 0;
    __syncthreads();
    s[t] += v;
    __syncthreads();
  }
  if (t < NB) bsum[t] = s[t] - c;  // exclusive
}

__global__ __launch_bounds__(256) void scan3_k(int* __restrict__ off,
    const int* __restrict__ bsum, int N) {
  int i = blockIdx.x * 256 + threadIdx.x;
  if (i < N) off[i + 1] += bsum[blockIdx.x];
  if (i == 0) off[0] = 0;
}

// fill using atomicSub on cnt (cnt is dead after scan): first edge lands at off[d].
__global__ __launch_bounds__(256) void fill_k(const int* __restrict__ src,
    const int* __restrict__ dst, const int* __restrict__ off,
    int* __restrict__ cnt, int* __restrict__ csr, int E) {
  int e = blockIdx.x * 256 + threadIdx.x;
  if (e < E) {
    int d = dst[e];
    int old = atomicSub(&cnt[d * PAD], 1);
    csr[off[d + 1] - old] = src[e];
  }
}

__global__ void root_k(const int* __restrict__ root, int* __restrict__ egof, int G) {
  int g = threadIdx.x;
  if (g < G) egof[root[g]] = 1;
}

// h0 = [x | deg_table[min(deg,128)] | ego], row stride 72; segmented pool into pool0.
__global__ __launch_bounds__(256) void h0_k(const float* __restrict__ x,
    const float* __restrict__ deg_table, const int* __restrict__ deg,
    const int* __restrict__ egof, const int* __restrict__ batch,
    float* __restrict__ h0, float* __restrict__ pool0, int N) {
  int w = threadIdx.x >> 6, f = threadIdx.x & 63;
  int base = blockIdx.x * CHUNK;
  int end = min(base + CHUNK, N);
  float accum = 0.0f, accum64 = 0.0f;
  int curg = -1;
  for (int n0 = base + w; n0 < end; n0 += 4) {
    int n = __builtin_amdgcn_readfirstlane(n0);
    float v;
    if (f < 32) {
      v = x[n * 32 + f];
    } else {
      int d = deg[n * PAD];
      if (d > 128) d = 128;
      v = deg_table[d * 32 + (f - 32)];
    }
    h0[(size_t)n * 72 + f] = v;
    float e = 0.0f;
    if (f == 0) {
      e = egof[n] ? 1.0f : 0.0f;
      h0[(size_t)n * 72 + 64] = e;
    }
    int g = batch[n];
    if (g != curg) {
      if (curg >= 0) {
        atomicAdd(&pool0[curg * 72 + f], accum);
        if (f == 0 && accum64 != 0.0f) atomicAdd(&pool0[curg * 72 + 64], accum64);
      }
      curg = g;
      accum = v;
      accum64 = e;
    } else {
      accum += v;
      accum64 += e;
    }
  }
  if (curg >= 0) {
    atomicAdd(&pool0[curg * 72 + f], accum);
    if (f == 0 && accum64 != 0.0f) atomicAdd(&pool0[curg * 72 + 64], accum64);
  }
}

// ---------------- layer1: agg + GEMM1 + sums0, wave-per-node, barrier-free ----------------
template <int FEATS, int STRIDE>
__global__ __launch_bounds__(256) void layer1_k(const float* __restrict__ h,
    const int* __restrict__ off, const int* __restrict__ csr,
    const float* __restrict__ W1, const float* __restrict__ B1,
    float* __restrict__ z1, float* __restrict__ sums, int N) {
  __shared__ float Wsh[FEATS * 64];
  __shared__ float ls[256], lq[256];
  const int t = threadIdx.x;
  for (int i = t; i < FEATS * 64; i += 256) Wsh[i] = W1[i];
  __syncthreads();
  const int w = t >> 6, lane = t & 63;
  const float bj = B1[lane];
  float s = 0.0f, q = 0.0f;
  const int step = gridDim.x * 4;
  for (int n0 = blockIdx.x * 4 + w; n0 < N; n0 += step) {
    const int n = __builtin_amdgcn_readfirstlane(n0);
    const float* row = h + (size_t)n * STRIDE;
    float z = row[lane];
    float z64 = 0.0f;
    if (FEATS == 65) { if (lane == 0) z64 = row[64]; }
    const int k1 = off[n + 1];
    int k = off[n];
    for (; k + 8 <= k1; k += 8) {
      int i0 = csr[k], i1 = csr[k + 1], i2 = csr[k + 2], i3 = csr[k + 3];
      int i4 = csr[k + 4], i5 = csr[k + 5], i6 = csr[k + 6], i7 = csr[k + 7];
      const float* r0 = h + (size_t)i0 * STRIDE;
      const float* r1 = h + (size_t)i1 * STRIDE;
      const float* r2 = h + (size_t)i2 * STRIDE;
      const float* r3 = h + (size_t)i3 * STRIDE;
      const float* r4 = h + (size_t)i4 * STRIDE;
      const float* r5 = h + (size_t)i5 * STRIDE;
      const float* r6 = h + (size_t)i6 * STRIDE;
      const float* r7 = h + (size_t)i7 * STRIDE;
      float v0 = r0[lane], v1 = r1[lane], v2 = r2[lane], v3 = r3[lane];
      float v4 = r4[lane], v5 = r5[lane], v6 = r6[lane], v7 = r7[lane];
      if (FEATS == 65) {
        if (lane == 0)
          z64 += ((r0[64] + r1[64]) + (r2[64] + r3[64])) +
                 ((r4[64] + r5[64]) + (r6[64] + r7[64]));
      }
      z += ((v0 + v1) + (v2 + v3)) + ((v4 + v5) + (v6 + v7));
    }
    for (; k < k1; k++) {
      const float* r0 = h + (size_t)csr[k] * STRIDE;
      z += r0[lane];
      if (FEATS == 65) { if (lane == 0) z64 += r0[64]; }
    }
    float a0 = bj, a1 = 0.0f, a2 = 0.0f, a3 = 0.0f;
#pragma unroll
    for (int k2 = 0; k2 < 64; k2 += 4) {
      a0 += BCAST(z, k2) * Wsh[k2 * 64 + lane];
      a1 += BCAST(z, k2 + 1) * Wsh[(k2 + 1) * 64 + lane];
      a2 += BCAST(z, k2 + 2) * Wsh[(k2 + 2) * 64 + lane];
      a3 += BCAST(z, k2 + 3) * Wsh[(k2 + 3) * 64 + lane];
    }
    if (FEATS == 65) a0 += BCAST(z64, 0) * Wsh[64 * 64 + lane];
    float acc = (a0 + a1) + (a2 + a3);
    z1[(size_t)n * 64 + lane] = acc;
    s += acc;
    q += acc * acc;
  }
  ls[t] = s; lq[t] = q;
  __syncthreads();
  if (t < 64) {
    float a = ls[t] + ls[64 + t] + ls[128 + t] + ls[192 + t];
    atomicAdd(&sums[(blockIdx.x & (NREP - 1)) * 128 + t], a);
  } else if (t < 128) {
    int f = t - 64;
    float a = lq[f] + lq[64 + f] + lq[128 + f] + lq[192 + f];
    atomicAdd(&sums[(blockIdx.x & (NREP - 1)) * 128 + 64 + f], a);
  }
}

// ---------------- layer2: BN0+ReLU + GEMM2 + sums1, wave-per-node, barrier-free ----------------
__global__ __launch_bounds__(256) void layer2_k(const float* __restrict__ z1,
    const float* __restrict__ W2, const float* __restrict__ B2,
    const float* __restrict__ sums0, const float* __restrict__ g0,
    const float* __restrict__ be0, float invN,
    float* __restrict__ z2, float* __restrict__ sums1, int N) {
  __shared__ float Wsh[64 * 64];
  __shared__ float redu[128];
  __shared__ float scs[64], shs[64];
  __shared__ float ls[256], lq[256];
  const int t = threadIdx.x;
  for (int i = t; i < 64 * 64; i += 256) Wsh[i] = W2[i];
  if (t < 128) {
    float a = 0.0f;
#pragma unroll
    for (int b = 0; b < NREP; b++) a += sums0[b * 128 + t];
    redu[t] = a;
  }
  __syncthreads();
  if (t < 64) {
    float m = redu[t] * invN;
    float var = redu[64 + t] * invN - m * m;
    float sc = g0[t] * rsqrtf(var + 1e-5f);
    scs[t] = sc;
    shs[t] = be0[t] - m * sc;
  }
  __syncthreads();
  const int w = t >> 6, lane = t & 63;
  const float sc = scs[lane], sh = shs[lane];
  const float bj = B2[lane];
  float s = 0.0f, q = 0.0f;
  const int step = gridDim.x * 4;
  for (int n0 = blockIdx.x * 4 + w; n0 < N; n0 += step) {
    const int n = __builtin_amdgcn_readfirstlane(n0);
    float v = z1[(size_t)n * 64 + lane];
    v = fmaxf(v * sc + sh, 0.0f);
    float a0 = bj, a1 = 0.0f, a2 = 0.0f, a3 = 0.0f;
#pragma unroll
    for (int k2 = 0; k2 < 64; k2 += 4) {
      a0 += BCAST(v, k2) * Wsh[k2 * 64 + lane];
      a1 += BCAST(v, k2 + 1) * Wsh[(k2 + 1) * 64 + lane];
      a2 += BCAST(v, k2 + 2) * Wsh[(k2 + 2) * 64 + lane];
      a3 += BCAST(v, k2 + 3) * Wsh[(k2 + 3) * 64 + lane];
    }
    float acc = (a0 + a1) + (a2 + a3);
    z2[(size_t)n * 64 + lane] = acc;
    s += acc;
    q += acc * acc;
  }
  ls[t] = s; lq[t] = q;
  __syncthreads();
  if (t < 64) {
    float a = ls[t] + ls[64 + t] + ls[128 + t] + ls[192 + t];
    atomicAdd(&sums1[(blockIdx.x & (NREP - 1)) * 128 + t], a);
  } else if (t < 128) {
    int f = t - 64;
    float a = lq[f] + lq[64 + f] + lq[128 + f] + lq[192 + f];
    atomicAdd(&sums1[(blockIdx.x & (NREP - 1)) * 128 + 64 + f], a);
  }
}

// ---------------- stats of relu(bn1(z2)) -> sums2 ----------------
__global__ __launch_bounds__(256) void statsbn_k(const float* __restrict__ z2,
    const float* __restrict__ sums1, const float* __restrict__ g1,
    const float* __restrict__ be1, float invN, float* __restrict__ sums2, int N) {
  __shared__ float redu[128];
  __shared__ float scs[64], shs[64];
  __shared__ float ls[256], lq[256];
  int t = threadIdx.x;
  if (t < 128) {
    float a = 0.0f;
#pragma unroll
    for (int b = 0; b < NREP; b++) a += sums1[b * 128 + t];
    redu[t] = a;
  }
  __syncthreads();
  if (t < 64) {
    float m = redu[t] * invN;
    float var = redu[64 + t] * invN - m * m;
    float sc = g1[t] * rsqrtf(var + 1e-5f);
    scs[t] = sc;
    shs[t] = be1[t] - m * sc;
  }
  __syncthreads();
  int f = t & 63, r = t >> 6;
  float sc = scs[f], sh = shs[f];
  float s = 0.0f, q = 0.0f;
  for (int n = blockIdx.x * 4 + r; n < N; n += gridDim.x * 4) {
    float v = z2[(size_t)n * 64 + f];
    v = fmaxf(v * sc + sh, 0.0f);
    s += v;
    q += v * v;
  }
  ls[t] = s; lq[t] = q;
  __syncthreads();
  if (t < 64) {
    float a = ls[t] + ls[64 + t] + ls[128 + t] + ls[192 + t];
    atomicAdd(&sums2[(blockIdx.x & (NREP - 1)) * 128 + t], a);
  } else if (t < 128) {
    int ff = t - 64;
    float a = lq[ff] + lq[64 + ff] + lq[128 + ff] + lq[192 + ff];
    atomicAdd(&sums2[(blockIdx.x & (NREP - 1)) * 128 + 64 + ff], a);
  }
}

// ---------------- h_out = relu(bn2(relu(bn1(z2)))) + segmented pool ----------------
__global__ __launch_bounds__(256) void apply_k(const float* __restrict__ z2,
    const float* __restrict__ sums1, const float* __restrict__ g1, const float* __restrict__ be1,
    const float* __restrict__ sums2, const float* __restrict__ g2, const float* __restrict__ be2,
    float invN, const int* __restrict__ batch, float* __restrict__ hout,
    float* __restrict__ pool, int N, int writeH) {
  __shared__ float red1[128], red2[128];
  __shared__ float sc1s[64], sh1s[64], sc2s[64], sh2s[64];
  int t = threadIdx.x;
  if (t < 128) {
    float a = 0.0f, c = 0.0f;
#pragma unroll
    for (int b = 0; b < NREP; b++) { a += sums1[b * 128 + t]; c += sums2[b * 128 + t]; }
    red1[t] = a;
    red2[t] = c;
  }
  __syncthreads();
  if (t < 64) {
    float m = red1[t] * invN;
    float var = red1[64 + t] * invN - m * m;
    float sc = g1[t] * rsqrtf(var + 1e-5f);
    sc1s[t] = sc;
    sh1s[t] = be1[t] - m * sc;
    m = red2[t] * invN;
    var = red2[64 + t] * invN - m * m;
    sc = g2[t] * rsqrtf(var + 1e-5f);
    sc2s[t] = sc;
    sh2s[t] = be2[t] - m * sc;
  }
  __syncthreads();
  int w = t >> 6, f = t & 63;
  float sc1 = sc1s[f], sh1 = sh1s[f], sc2 = sc2s[f], sh2 = sh2s[f];
  int base = blockIdx.x * CHUNK;
  int end = min(base + CHUNK, N);
  float accum = 0.0f;
  int curg = -1;
  for (int n0 = base + w; n0 < end; n0 += 4) {
    int n = __builtin_amdgcn_readfirstlane(n0);
    float v = z2[(size_t)n * 64 + f];
    v = fmaxf(v * sc1 + sh1, 0.0f);
    v = fmaxf(v * sc2 + sh2, 0.0f);
    if (writeH) hout[(size_t)n * 64 + f] = v;
    int g = batch[n];
    if (g != curg) {
      if (curg >= 0) atomicAdd(&pool[curg * 64 + f], accum);
      curg = g;
      accum = v;
    } else {
      accum += v;
    }
  }
  if (curg >= 0) atomicAdd(&pool[curg * 64 + f], accum);
}

// ---------------- all 6 prediction heads + L2 normalize; one wave per graph ----------------
__global__ __launch_bounds__(64) void prednorm_k(const float* __restrict__ pool0,
    const float* __restrict__ pools, const float* __restrict__ pw0,
    const float* __restrict__ pb0, const float* __restrict__ pwr,
    const float* __restrict__ pbr, float* __restrict__ out, int G) {
  int g = blockIdx.x;
  int j = threadIdx.x;
  float acc = 0.0f;
  if (j < 32) {
    acc = pb0[j];
    for (int k = 0; k < 65; k++) acc += pool0[g * 72 + k] * pw0[k * 32 + j];
    for (int l = 0; l < 5; l++) {
      acc += pbr[l * 32 + j];
      const float* pl = pools + (size_t)l * G * 64 + (size_t)g * 64;
      const float* wl = pwr + (size_t)l * 64 * 32;
      for (int k = 0; k < 64; k++) acc += pl[k] * wl[k * 32 + j];
    }
  }
  float s = acc * acc;
  for (int o = 16; o > 0; o >>= 1) s += __shfl_xor(s, o);
  float nrm = fmaxf(sqrtf(s), 1e-5f);
  if (j < 32) out[g * 32 + j] = acc / nrm;
}

extern "C" void kernel_launch(void* const* d_in, const int* in_sizes, int n_in,
                              void* d_out, int out_size, void* d_ws, size_t ws_size,
                              hipStream_t stream) {
  (void)n_in; (void)out_size; (void)ws_size;
  const float* x          = (const float*)d_in[0];
  const int*   edge_index = (const int*)d_in[1];
  const int*   batch      = (const int*)d_in[2];
  const int*   root       = (const int*)d_in[3];
  const float* deg_table  = (const float*)d_in[4];
  const float* w1_0       = (const float*)d_in[5];
  const float* b1_0       = (const float*)d_in[6];
  const float* w2_0       = (const float*)d_in[7];
  const float* b2_0       = (const float*)d_in[8];
  const float* w1_rest    = (const float*)d_in[9];
  const float* b1_rest    = (const float*)d_in[10];
  const float* w2_rest    = (const float*)d_in[11];
  const float* b2_rest    = (const float*)d_in[12];
  const float* bn_gamma   = (const float*)d_in[13];
  const float* bn_beta    = (const float*)d_in[14];
  const float* pred_w0    = (const float*)d_in[15];
  const float* pred_b0    = (const float*)d_in[16];
  const float* pred_w_rest = (const float*)d_in[17];
  const float* pred_b_rest = (const float*)d_in[18];

  const int N = in_sizes[0] / 32;
  const int E = in_sizes[1] / 2;
  const int G = in_sizes[3];
  const int* src = edge_index;
  const int* dst = edge_index + E;
  const float invN = 1.0f / N;

  // ---- workspace carve-up (256B aligned) ----
  char* w = (char*)d_ws;
  auto alloc = [&](size_t bytes) {
    char* p = w;
    w += (bytes + 255) & ~(size_t)255;
    return p;
  };
  int* d_deg  = (int*)alloc((size_t)N * PAD * 4);
  int* d_cnt  = (int*)alloc((size_t)N * PAD * 4);
  int* d_egof = (int*)alloc((size_t)N * 4);
  char* zero_int_end = w;
  int* d_off  = (int*)alloc((size_t)(N + 1) * 4);
  int* d_bsum = (int*)alloc(256 * 4);
  int* d_csr  = (int*)alloc((size_t)E * 4);
  float* fsums = (float*)alloc((size_t)15 * NREP * 128 * 4);
  float* fpool = (float*)alloc((size_t)(G * 72 + 5 * G * 64) * 4);
  char* zero_f_end = w;
  float* fh0 = (float*)alloc((size_t)N * 72 * 4);
  float* fB1 = (float*)alloc((size_t)N * 64 * 4);  // z1
  float* fB2 = (float*)alloc((size_t)N * 64 * 4);  // z2
  float* fB3 = (float*)alloc((size_t)N * 64 * 4);  // h ping-pong with fh0

  hipMemsetAsync(d_deg, 0, (size_t)(zero_int_end - (char*)d_deg), stream);
  hipMemsetAsync(fsums, 0, (size_t)(zero_f_end - (char*)fsums), stream);

  const int ebl = (E + 255) / 256;
  const int nb  = (N + 255) / 256;
  const int ncb = (N + CHUNK - 1) / CHUNK;   // ~782 blocks for h0/apply

  count_k<<<ebl, 256, 0, stream>>>(src, dst, d_deg, d_cnt, E);
  scan1_k<<<nb, 256, 0, stream>>>(d_cnt, d_off, d_bsum, N);
  scan2_k<<<1, 256, 0, stream>>>(d_bsum, nb);
  scan3_k<<<nb, 256, 0, stream>>>(d_off, d_bsum, N);
  fill_k<<<ebl, 256, 0, stream>>>(src, dst, d_off, d_cnt, d_csr, E);
  root_k<<<1, 256, 0, stream>>>(root, d_egof, G);
  h0_k<<<ncb, 256, 0, stream>>>(x, deg_table, d_deg, d_egof, batch, fh0, fpool, N);

  float* pools = fpool + G * 72;
  const float* hcur = fh0;
  float* hnext = fB3;
  for (int l = 0; l < 5; l++) {
    const float* w1 = (l == 0) ? w1_0 : w1_rest + (size_t)(l - 1) * 64 * 64;
    const float* b1 = (l == 0) ? b1_0 : b1_rest + (size_t)(l - 1) * 64;
    const float* w2 = (l == 0) ? w2_0 : w2_rest + (size_t)(l - 1) * 64 * 64;
    const float* b2 = (l == 0) ? b2_0 : b2_rest + (size_t)(l - 1) * 64;
    float* sums0 = fsums + (size_t)(l * 3 + 0) * NREP * 128;
    float* sums1 = fsums + (size_t)(l * 3 + 1) * NREP * 128;
    float* sums2 = fsums + (size_t)(l * 3 + 2) * NREP * 128;
    const float* g0 = bn_gamma + (l * 3 + 0) * 64;
    const float* be0 = bn_beta + (l * 3 + 0) * 64;
    const float* g1 = bn_gamma + (l * 3 + 1) * 64;
    const float* be1 = bn_beta + (l * 3 + 1) * 64;
    const float* g2 = bn_gamma + (l * 3 + 2) * 64;
    const float* be2 = bn_beta + (l * 3 + 2) * 64;

    if (l == 0)
      layer1_k<65, 72><<<2048, 256, 0, stream>>>(hcur, d_off, d_csr, w1, b1, fB1, sums0, N);
    else
      layer1_k<64, 64><<<2048, 256, 0, stream>>>(hcur, d_off, d_csr, w1, b1, fB1, sums0, N);
    layer2_k<<<2048, 256, 0, stream>>>(fB1, w2, b2, sums0, g0, be0, invN, fB2, sums1, N);
    statsbn_k<<<1024, 256, 0, stream>>>(fB2, sums1, g1, be1, invN, sums2, N);
    float* pool_l = pools + (size_t)l * G * 64;
    apply_k<<<ncb, 256, 0, stream>>>(fB2, sums1, g1, be1, sums2, g2, be2, invN,
                                     batch, hnext, pool_l, N, (l < 4) ? 1 : 0);
    const float* tmp = hcur;
    hcur = hnext;
    hnext = (float*)tmp;
  }
  prednorm_k<<<G, 64, 0, stream>>>(fpool, pools, pred_w0, pred_b0,
                                   pred_w_rest, pred_b_rest, (float*)d_out, G);
}